// Round 10
// baseline (401.323 us; speedup 1.0000x reference)
//
#include <hip/hip_runtime.h>
#include <hip/hip_bf16.h>
#include <math.h>

#define B_   2
#define S_   2048
#define H_   16
#define DH_  64
#define DM_  1024
#define M_   (B_*S_)   // 4096
#define PV_  512
#define LOG2E 1.4426950408889634f

typedef __attribute__((ext_vector_type(8))) short bf16x8;
typedef __attribute__((ext_vector_type(4))) float f32x4;

__device__ __forceinline__ float b2f(unsigned short u) {
  union { unsigned int i; float f; } v; v.i = ((unsigned int)u) << 16; return v.f;
}
__device__ __forceinline__ unsigned short f2b(float f) {
  union { float f; unsigned int i; } v; v.f = f;
  return (unsigned short)((v.i + 0x7fffu + ((v.i >> 16) & 1u)) >> 16);  // RNE
}
__device__ __forceinline__ f32x4 mfma16(bf16x8 a, bf16x8 b, f32x4 c) {
  return __builtin_amdgcn_mfma_f32_16x16x32_bf16(a, b, c, 0, 0, 0);
}

// ---------------- RoPE sin/cos table: tab[s][i] = {sin, cos} (float2), i in [0,32)
__global__ void k_ropetab(float* tab) {
  int idx = blockIdx.x * 256 + threadIdx.x;       // s*32 + i
  if (idx >= S_ * 32) return;
  int s = idx >> 5, i = idx & 31;
  double inv = exp(-((double)(2 * i) / 64.0) * log(10000.0));
  double f = (double)s * inv;
  tab[idx * 2 + 0] = (float)sin(f);
  tab[idx * 2 + 1] = (float)cos(f);
}

// ---------------- one-time: x (f32) -> xb (bf16), 4096x1024 ---------------------
__global__ __launch_bounds__(256) void k_xcast(const float* __restrict__ x,
                                               unsigned short* __restrict__ xb) {
  int idx = blockIdx.x * 256 + threadIdx.x;       // chunks of 8
  const float4 f0 = *(const float4*)(x + (size_t)idx * 8);
  const float4 f1 = *(const float4*)(x + (size_t)idx * 8 + 4);
  union { uint4 u; unsigned short s[8]; } o;
  o.s[0] = f2b(f0.x); o.s[1] = f2b(f0.y); o.s[2] = f2b(f0.z); o.s[3] = f2b(f0.w);
  o.s[4] = f2b(f1.x); o.s[5] = f2b(f1.y); o.s[6] = f2b(f1.z); o.s[7] = f2b(f1.w);
  *(uint4*)(xb + (size_t)idx * 8) = o.u;
}

// ---------------- one-time: Wt[n][k] = bf16(W[k][n]), 1024x1024 ------------------
__global__ __launch_bounds__(256) void k_prepw(const float* __restrict__ W,
                                               unsigned short* __restrict__ Wt) {
  int r0 = blockIdx.y * 64, c0 = blockIdx.x * 64;  // r=k, c=n
  __shared__ unsigned short t[64][65];
  #pragma unroll
  for (int p = 0; p < 16; ++p) {
    int idx = p * 256 + threadIdx.x;
    int i = idx >> 6, j = idx & 63;
    t[i][j] = f2b(W[(size_t)(r0 + i) * DM_ + c0 + j]);
  }
  __syncthreads();
  #pragma unroll
  for (int p = 0; p < 16; ++p) {
    int idx = p * 256 + threadIdx.x;
    int i = idx >> 6, j = idx & 63;
    Wt[(size_t)(c0 + i) * DM_ + r0 + j] = t[j][i];
  }
}

// ---------------- fast GEMM: C = A[M][K](bf16) * Wt[N][K]^T(bf16) + bias ---------
// 128x128 tile, BK=32, double-buffered LDS, ONE barrier per K-step.
// ROPE: epilogue -> [b,h,s,d] bf16, scale folded. OF32: f32 out else bf16.
template<bool ROPE, bool OF32>
__global__ __launch_bounds__(256) void k_gemm2(const unsigned short* __restrict__ A,
                                               const unsigned short* __restrict__ Wt,
                                               const float* __restrict__ bias,
                                               void* __restrict__ Cv,
                                               const float* __restrict__ tab,
                                               int M, int N, int K, float scale) {
  __shared__ unsigned short Alds[2][128][40];
  __shared__ unsigned short Blds[2][128][40];
  int lane = threadIdx.x & 63, w = threadIdx.x >> 6;
  int wr = w >> 1, wc = w & 1;
  int l16 = lane & 15, lq = lane >> 4;
  int m0 = blockIdx.y * 128, n0 = blockIdx.x * 128;

  f32x4 acc[4][4];
  #pragma unroll
  for (int a = 0; a < 4; ++a)
    #pragma unroll
    for (int b = 0; b < 4; ++b) acc[a][b] = (f32x4){0.f, 0.f, 0.f, 0.f};

  uint4 ar[2], br[2];
  // prologue: load step 0, write buf 0
  #pragma unroll
  for (int i = 0; i < 2; ++i) {
    int c = threadIdx.x + i * 256;
    int rr = c >> 2, ch = (c & 3) * 8;
    ar[i] = *(const uint4*)(A  + (size_t)(m0 + rr) * K + ch);
    br[i] = *(const uint4*)(Wt + (size_t)(n0 + rr) * K + ch);
  }
  #pragma unroll
  for (int i = 0; i < 2; ++i) {
    int c = threadIdx.x + i * 256;
    int rr = c >> 2, ch = (c & 3) * 8;
    *(uint4*)&Alds[0][rr][ch] = ar[i];
    *(uint4*)&Blds[0][rr][ch] = br[i];
  }

  int cur = 0;
  for (int k0 = 0; k0 < K; k0 += 32, cur ^= 1) {
    __syncthreads();                               // buf[cur] ready
    bool more = (k0 + 32 < K);
    if (more) {
      #pragma unroll
      for (int i = 0; i < 2; ++i) {
        int c = threadIdx.x + i * 256;
        int rr = c >> 2, ch = (c & 3) * 8;
        ar[i] = *(const uint4*)(A  + (size_t)(m0 + rr) * K + k0 + 32 + ch);
        br[i] = *(const uint4*)(Wt + (size_t)(n0 + rr) * K + k0 + 32 + ch);
      }
    }
    bf16x8 af[4], bf_[4];
    #pragma unroll
    for (int mi = 0; mi < 4; ++mi) af[mi] = *(const bf16x8*)&Alds[cur][wr * 64 + mi * 16 + l16][lq * 8];
    #pragma unroll
    for (int ni = 0; ni < 4; ++ni) bf_[ni] = *(const bf16x8*)&Blds[cur][wc * 64 + ni * 16 + l16][lq * 8];
    #pragma unroll
    for (int mi = 0; mi < 4; ++mi)
      #pragma unroll
      for (int ni = 0; ni < 4; ++ni)
        acc[mi][ni] = mfma16(af[mi], bf_[ni], acc[mi][ni]);
    if (more) {
      #pragma unroll
      for (int i = 0; i < 2; ++i) {
        int c = threadIdx.x + i * 256;
        int rr = c >> 2, ch = (c & 3) * 8;
        *(uint4*)&Alds[cur ^ 1][rr][ch] = ar[i];
        *(uint4*)&Blds[cur ^ 1][rr][ch] = br[i];
      }
    }
  }

  // epilogue. C/D layout: col=lane&15, row=(lane>>4)*4+j (m89)
  if (!ROPE) {
    #pragma unroll
    for (int ni = 0; ni < 4; ++ni) {
      int col = n0 + wc * 64 + ni * 16 + l16;
      float bv = bias[col];
      #pragma unroll
      for (int mi = 0; mi < 4; ++mi)
        #pragma unroll
        for (int j = 0; j < 4; ++j) {
          int row = m0 + wr * 64 + mi * 16 + lq * 4 + j;
          size_t idx = (size_t)row * N + col;
          float v = acc[mi][ni][j] + bv;
          if (OF32) ((float*)Cv)[idx] = v;
          else      ((unsigned short*)Cv)[idx] = f2b(v);
        }
    }
  } else {
    #pragma unroll
    for (int ni = 0; ni < 4; ++ni) {
      int col = n0 + wc * 64 + ni * 16 + l16;        // 0..1023 = h*64 + d
      int h = col >> 6, d = col & 63;
      float bv = bias[col];
      #pragma unroll
      for (int mi = 0; mi < 4; ++mi)
        #pragma unroll
        for (int j = 0; j < 4; ++j) {
          int row = m0 + wr * 64 + mi * 16 + lq * 4 + j;
          int s = row & (S_ - 1), b = row >> 11;
          float v = acc[mi][ni][j] + bv;
          float p = __shfl_xor(v, 1, 64);            // partner column value
          float2 sc = *(const float2*)(tab + ((size_t)s * 32 + (d >> 1)) * 2);
          float o = (d & 1) ? (v * sc.y + p * sc.x)
                            : (v * sc.y - p * sc.x);
          ((unsigned short*)Cv)[(((size_t)(b * H_ + h) * S_) + s) * DH_ + d] = f2b(o * scale);
        }
    }
  }
}

// ---------------- legacy GEMM (fallback when ws too small) ----------------------
template<bool AF32, bool ROPE, bool OF32>
__global__ __launch_bounds__(256) void k_gemmW(const void* __restrict__ Av,
                                               const float* __restrict__ W,
                                               const float* __restrict__ bias,
                                               void* __restrict__ Cv,
                                               const float* __restrict__ tab,
                                               int M, int N, int K, float scale) {
  __shared__ unsigned short Alds[128][40];
  __shared__ unsigned short Blds[128][40];
  int lane = threadIdx.x & 63, w = threadIdx.x >> 6;
  int wr = w >> 1, wc = w & 1;
  int l16 = lane & 15, lq = lane >> 4;
  int m0 = blockIdx.y * 128, n0 = blockIdx.x * 128;
  f32x4 acc[4][4];
  #pragma unroll
  for (int a = 0; a < 4; ++a)
    #pragma unroll
    for (int b = 0; b < 4; ++b) acc[a][b] = (f32x4){0.f, 0.f, 0.f, 0.f};

  for (int k0 = 0; k0 < K; k0 += 32) {
    __syncthreads();
    #pragma unroll
    for (int i = 0; i < 2; ++i) {
      int c = threadIdx.x + i * 256;
      int r = c >> 2, ch = (c & 3) * 8;
      size_t base = (size_t)(m0 + r) * K + k0 + ch;
      if (AF32) {
        const float* A = (const float*)Av;
        float4 f0 = *(const float4*)(A + base);
        float4 f1 = *(const float4*)(A + base + 4);
        unsigned short* dst = &Alds[r][ch];
        dst[0] = f2b(f0.x); dst[1] = f2b(f0.y); dst[2] = f2b(f0.z); dst[3] = f2b(f0.w);
        dst[4] = f2b(f1.x); dst[5] = f2b(f1.y); dst[6] = f2b(f1.z); dst[7] = f2b(f1.w);
      } else {
        *(uint4*)&Alds[r][ch] = *(const uint4*)((const unsigned short*)Av + base);
      }
    }
    #pragma unroll
    for (int i = 0; i < 2; ++i) {
      int c = threadIdx.x + i * 256;
      int kk = c >> 4, n8 = (c & 15) * 8;
      size_t base = (size_t)(k0 + kk) * N + n0 + n8;
      float4 w0 = *(const float4*)(W + base);
      float4 w1 = *(const float4*)(W + base + 4);
      Blds[n8 + 0][kk] = f2b(w0.x); Blds[n8 + 1][kk] = f2b(w0.y);
      Blds[n8 + 2][kk] = f2b(w0.z); Blds[n8 + 3][kk] = f2b(w0.w);
      Blds[n8 + 4][kk] = f2b(w1.x); Blds[n8 + 5][kk] = f2b(w1.y);
      Blds[n8 + 6][kk] = f2b(w1.z); Blds[n8 + 7][kk] = f2b(w1.w);
    }
    __syncthreads();
    bf16x8 af[4], bf_[4];
    #pragma unroll
    for (int mi = 0; mi < 4; ++mi) af[mi] = *(const bf16x8*)&Alds[wr * 64 + mi * 16 + l16][lq * 8];
    #pragma unroll
    for (int ni = 0; ni < 4; ++ni) bf_[ni] = *(const bf16x8*)&Blds[wc * 64 + ni * 16 + l16][lq * 8];
    #pragma unroll
    for (int mi = 0; mi < 4; ++mi)
      #pragma unroll
      for (int ni = 0; ni < 4; ++ni)
        acc[mi][ni] = mfma16(af[mi], bf_[ni], acc[mi][ni]);
  }
  if (!ROPE) {
    #pragma unroll
    for (int ni = 0; ni < 4; ++ni) {
      int col = n0 + wc * 64 + ni * 16 + l16;
      float bv = bias[col];
      #pragma unroll
      for (int mi = 0; mi < 4; ++mi)
        #pragma unroll
        for (int j = 0; j < 4; ++j) {
          int row = m0 + wr * 64 + mi * 16 + lq * 4 + j;
          size_t idx = (size_t)row * N + col;
          float v = acc[mi][ni][j] + bv;
          if (OF32) ((float*)Cv)[idx] = v;
          else      ((unsigned short*)Cv)[idx] = f2b(v);
        }
    }
  } else {
    #pragma unroll
    for (int ni = 0; ni < 4; ++ni) {
      int col = n0 + wc * 64 + ni * 16 + l16;
      int h = col >> 6, d = col & 63;
      float bv = bias[col];
      #pragma unroll
      for (int mi = 0; mi < 4; ++mi)
        #pragma unroll
        for (int j = 0; j < 4; ++j) {
          int row = m0 + wr * 64 + mi * 16 + lq * 4 + j;
          int s = row & (S_ - 1), b = row >> 11;
          float v = acc[mi][ni][j] + bv;
          float p = __shfl_xor(v, 1, 64);
          float2 sc = *(const float2*)(tab + ((size_t)s * 32 + (d >> 1)) * 2);
          float o = (d & 1) ? (v * sc.y + p * sc.x)
                            : (v * sc.y - p * sc.x);
          ((unsigned short*)Cv)[(((size_t)(b * H_ + h) * S_) + s) * DH_ + d] = f2b(o * scale);
        }
    }
  }
}

// ---------------- V: [b,s,h,d] -> Vt[b,h,d,s] (bf16 workspace) ------------------
__global__ __launch_bounds__(256) void k_vtrans(const unsigned short* __restrict__ Vp,
                                                unsigned short* __restrict__ Vt) {
  int bid = blockIdx.x;
  int st = bid & 31; int bh = bid >> 5; int h = bh & 15; int b = bh >> 4;
  int s0 = st * 64;
  __shared__ unsigned short t[64][72];
  #pragma unroll
  for (int i = 0; i < 2; ++i) {
    int c = threadIdx.x + i * 256;
    int r = c >> 3, ch = (c & 7) * 8;
    *(uint4*)&t[r][ch] = *(const uint4*)(Vp + (size_t)(b * S_ + s0 + r) * DM_ + h * DH_ + ch);
  }
  __syncthreads();
  #pragma unroll
  for (int i = 0; i < 2; ++i) {
    int c = threadIdx.x + i * 256;
    int dr = c >> 3, ch = (c & 7) * 8;
    union { uint4 u; unsigned short x[8]; } tb;
    #pragma unroll
    for (int e = 0; e < 8; ++e) tb.x[e] = t[ch + e][dr];
    *(uint4*)(Vt + ((size_t)bh * DH_ + dr) * S_ + s0 + ch) = tb.u;
  }
}

// ---------------- MFMA flash attention, double-buffered, log2-domain ------------
// block = (b, h, 64-row q tile); 4 waves, each owns 16 q rows.
// Qr pre-scaled by 0.125*LOG2E; bias column staged *LOG2E; p = exp2(s - m).
__global__ __launch_bounds__(256) void k_attn(const unsigned short* __restrict__ Qr,
                                              const unsigned short* __restrict__ Kr,
                                              const unsigned short* __restrict__ Vt,
                                              const int* __restrict__ dist,
                                              const float* __restrict__ table,
                                              unsigned short* __restrict__ AO) {
  int bid = blockIdx.x;                            // (b*16+h)*32 + qt
  int qt = bid & 31; int bh = bid >> 5; int h = bh & 15; int b = bh >> 4;
  int lane = threadIdx.x & 63, w = threadIdx.x >> 6;
  int l16 = lane & 15, lq = lane >> 4;
  int q0 = qt * 64;

  __shared__ unsigned short Klds[2][64][72];       // [buf][key][d]
  __shared__ unsigned short Vlds[2][64][72];       // [buf][d][key]
  __shared__ unsigned short Plds[4][16][72];       // per-wave P[qrow][key]
  __shared__ float tlds[PV_];                      // bias column * LOG2E

  for (int i = threadIdx.x; i < PV_; i += 256) tlds[i] = table[i * H_ + h] * LOG2E;

  const unsigned short* Qbase = Qr + ((size_t)bh * S_ + q0 + w * 16 + l16) * DH_;
  bf16x8 aq0 = *(const bf16x8*)(Qbase + lq * 8);
  bf16x8 aq1 = *(const bf16x8*)(Qbase + 32 + lq * 8);

  f32x4 oacc[4];
  float m_[4], l_[4];                              // log2-domain max; per-lane l
  #pragma unroll
  for (int j = 0; j < 4; ++j) { m_[j] = -1e30f; l_[j] = 0.f; }
  #pragma unroll
  for (int td = 0; td < 4; ++td) oacc[td] = (f32x4){0.f, 0.f, 0.f, 0.f};

  const int* drow = dist + ((size_t)b * S_ + q0 + w * 16) * S_;
  const unsigned short* Ksrc0 = Kr + (size_t)bh * S_ * DH_;
  const unsigned short* Vsrc0 = Vt + (size_t)bh * DH_ * S_;

  // prologue: dist tile0, K/V tile0 -> regs -> buf0
  int dc[4][4], dn[4][4];
  #pragma unroll
  for (int j = 0; j < 4; ++j) {
    const int* dr = drow + (size_t)(lq * 4 + j) * S_;
    #pragma unroll
    for (int t = 0; t < 4; ++t) dc[j][t] = dr[t * 16 + l16];
  }
  uint4 kr[2], vr[2];
  #pragma unroll
  for (int i = 0; i < 2; ++i) {
    int c = threadIdx.x + i * 256;
    int r = c >> 3, ch = (c & 7) * 8;
    kr[i] = *(const uint4*)(Ksrc0 + (size_t)r * DH_ + ch);
    vr[i] = *(const uint4*)(Vsrc0 + (size_t)r * S_ + ch);
  }
  #pragma unroll
  for (int i = 0; i < 2; ++i) {
    int c = threadIdx.x + i * 256;
    int r = c >> 3, ch = (c & 7) * 8;
    *(uint4*)&Klds[0][r][ch] = kr[i];
    *(uint4*)&Vlds[0][r][ch] = vr[i];
  }

  int cur = 0;
  for (int kv = 0; kv < S_; kv += 64, cur ^= 1) {
    __syncthreads();                               // buf[cur] + tlds ready
    bool more = (kv + 64 < S_);
    if (more) {
      const unsigned short* Ksrc = Ksrc0 + (size_t)(kv + 64) * DH_;
      const unsigned short* Vsrc = Vsrc0 + kv + 64;
      #pragma unroll
      for (int i = 0; i < 2; ++i) {
        int c = threadIdx.x + i * 256;
        int r = c >> 3, ch = (c & 7) * 8;
        kr[i] = *(const uint4*)(Ksrc + (size_t)r * DH_ + ch);
        vr[i] = *(const uint4*)(Vsrc + (size_t)r * S_ + ch);
      }
      #pragma unroll
      for (int j = 0; j < 4; ++j) {
        const int* dr = drow + (size_t)(lq * 4 + j) * S_ + kv + 64;
        #pragma unroll
        for (int t = 0; t < 4; ++t) dn[j][t] = dr[t * 16 + l16];
      }
    }

    // S' = QK^T (log2 scale folded into Q)
    f32x4 sc[4];
    #pragma unroll
    for (int t = 0; t < 4; ++t) {
      bf16x8 bk0 = *(const bf16x8*)&Klds[cur][t * 16 + l16][lq * 8];
      bf16x8 bk1 = *(const bf16x8*)&Klds[cur][t * 16 + l16][32 + lq * 8];
      f32x4 z = (f32x4){0.f, 0.f, 0.f, 0.f};
      z = mfma16(aq0, bk0, z);
      z = mfma16(aq1, bk1, z);
      sc[t] = z;
    }

    // + bias (log2 domain, no clamp: dist in [0,512) by construction)
    float rm[4];
    #pragma unroll
    for (int j = 0; j < 4; ++j) {
      float best = -1e30f;
      #pragma unroll
      for (int t = 0; t < 4; ++t) {
        float s = sc[t][j] + tlds[dc[j][t]];
        sc[t][j] = s;
        best = fmaxf(best, s);
      }
      rm[j] = best;
    }

    // defer-max: rescale only if some lane's max grew past m + 8*LOG2E
    bool need = (rm[0] > m_[0] + 11.5416f) || (rm[1] > m_[1] + 11.5416f) ||
                (rm[2] > m_[2] + 11.5416f) || (rm[3] > m_[3] + 11.5416f);
    if (__any(need)) {
      #pragma unroll
      for (int off = 1; off < 16; off <<= 1) {
        #pragma unroll
        for (int j = 0; j < 4; ++j) rm[j] = fmaxf(rm[j], __shfl_xor(rm[j], off, 64));
      }
      #pragma unroll
      for (int j = 0; j < 4; ++j) {
        float mn = fmaxf(m_[j], rm[j]);
        float scl = exp2f(m_[j] - mn);
        l_[j] *= scl;
        #pragma unroll
        for (int td = 0; td < 4; ++td) oacc[td][j] *= scl;
        m_[j] = mn;
      }
    }

    // p = exp2(s' - m'); per-lane partial l
    float p[4][4];
    #pragma unroll
    for (int j = 0; j < 4; ++j) {
      float su = 0.f;
      #pragma unroll
      for (int t = 0; t < 4; ++t) {
        float e = exp2f(sc[t][j] - m_[j]);
        p[t][j] = e;
        su += e;
      }
      l_[j] += su;
    }

    // P -> per-wave LDS (same-wave RAW, no barrier)
    #pragma unroll
    for (int j = 0; j < 4; ++j)
      #pragma unroll
      for (int t = 0; t < 4; ++t)
        Plds[w][lq * 4 + j][t * 16 + l16] = f2b(p[t][j]);

    bf16x8 pa0 = *(const bf16x8*)&Plds[w][l16][lq * 8];
    bf16x8 pa1 = *(const bf16x8*)&Plds[w][l16][32 + lq * 8];
    #pragma unroll
    for (int td = 0; td < 4; ++td) {
      bf16x8 v0 = *(const bf16x8*)&Vlds[cur][td * 16 + l16][lq * 8];
      bf16x8 v1 = *(const bf16x8*)&Vlds[cur][td * 16 + l16][32 + lq * 8];
      oacc[td] = mfma16(pa0, v0, oacc[td]);
      oacc[td] = mfma16(pa1, v1, oacc[td]);
    }

    // write next tile into the other buffer; rotate dist regs
    if (more) {
      #pragma unroll
      for (int i = 0; i < 2; ++i) {
        int c = threadIdx.x + i * 256;
        int r = c >> 3, ch = (c & 7) * 8;
        *(uint4*)&Klds[cur ^ 1][r][ch] = kr[i];
        *(uint4*)&Vlds[cur ^ 1][r][ch] = vr[i];
      }
      #pragma unroll
      for (int j = 0; j < 4; ++j)
        #pragma unroll
        for (int t = 0; t < 4; ++t) dc[j][t] = dn[j][t];
    }
  }

  // final cross-lane l reduce, normalize, store
  #pragma unroll
  for (int off = 1; off < 16; off <<= 1) {
    #pragma unroll
    for (int j = 0; j < 4; ++j) l_[j] += __shfl_xor(l_[j], off, 64);
  }
  float inv[4];
  #pragma unroll
  for (int j = 0; j < 4; ++j) inv[j] = 1.f / l_[j];
  #pragma unroll
  for (int td = 0; td < 4; ++td) {
    #pragma unroll
    for (int j = 0; j < 4; ++j) {
      size_t row = (size_t)b * S_ + q0 + w * 16 + lq * 4 + j;
      AO[row * DM_ + h * DH_ + td * 16 + l16] = f2b(oacc[td][j] * inv[j]);
    }
  }
}

// --------------------------------------------------------------------------------
extern "C" void kernel_launch(void* const* d_in, const int* in_sizes, int n_in,
                              void* d_out, int out_size, void* d_ws, size_t ws_size,
                              hipStream_t stream) {
  const float* x    = (const float*)d_in[0];
  const int*   dist = (const int*)d_in[1];
  const float* Wq   = (const float*)d_in[2];
  const float* bq   = (const float*)d_in[3];
  const float* Wk   = (const float*)d_in[4];
  const float* bk   = (const float*)d_in[5];
  const float* Wv   = (const float*)d_in[6];
  const float* bv   = (const float*)d_in[7];
  const float* Wo   = (const float*)d_in[8];
  const float* bo   = (const float*)d_in[9];
  const float* tabb = (const float*)d_in[10];

  char* ws = (char*)d_ws;
  const size_t SZ_TAB = (size_t)S_ * 32 * 2 * 4;       // 512 KB
  const size_t SZ_T   = (size_t)M_ * DM_ * 2;          // 8 MB
  const size_t SZ_W   = (size_t)DM_ * DM_ * 2;         // 2 MB
  float* rtab = (float*)ws;
  size_t off = SZ_TAB;
  unsigned short* Qr   = (unsigned short*)(ws + off); off += SZ_T;
  unsigned short* Kr   = (unsigned short*)(ws + off); off += SZ_T;
  unsigned short* Vt   = (unsigned short*)(ws + off); off += SZ_T;
  unsigned short* VpAO = (unsigned short*)(ws + off); off += SZ_T;  // Vp, then AO
  unsigned short* Wtq  = (unsigned short*)(ws + off); off += SZ_W;
  unsigned short* Wtk  = (unsigned short*)(ws + off); off += SZ_W;
  unsigned short* Wtv  = (unsigned short*)(ws + off); off += SZ_W;
  unsigned short* Wto  = (unsigned short*)(ws + off); off += SZ_W;
  size_t off_prep = off;
  unsigned short* xb   = (unsigned short*)(ws + off); off += SZ_T;
  bool prep  = ws_size >= off_prep;                    // 40.5 MB: Wt path
  bool xcast = ws_size >= off;                         // 48.5 MB: + bf16 x

  const float QSCALE = 0.125f * LOG2E;                 // fold 1/sqrt(64) and log2e

  k_ropetab<<<dim3(256), dim3(256), 0, stream>>>(rtab);

  if (prep && xcast) {
    k_prepw<<<dim3(16, 16), 256, 0, stream>>>(Wq, Wtq);
    k_prepw<<<dim3(16, 16), 256, 0, stream>>>(Wk, Wtk);
    k_prepw<<<dim3(16, 16), 256, 0, stream>>>(Wv, Wtv);
    k_prepw<<<dim3(16, 16), 256, 0, stream>>>(Wo, Wto);
    k_xcast<<<dim3(M_ * DM_ / 8 / 256), 256, 0, stream>>>(x, xb);
    k_gemm2<true, false><<<dim3(8, 32), 256, 0, stream>>>(xb, Wtq, bq, Qr, rtab, M_, DM_, DM_, QSCALE);
    k_gemm2<true, false><<<dim3(8, 32), 256, 0, stream>>>(xb, Wtk, bk, Kr, rtab, M_, DM_, DM_, 1.0f);
    k_gemm2<false, false><<<dim3(8, 32), 256, 0, stream>>>(xb, Wtv, bv, VpAO, rtab, M_, DM_, DM_, 1.0f);
  } else {
    k_gemmW<true, true, false><<<dim3(8, 32), 256, 0, stream>>>(x, Wq, bq, Qr, rtab, M_, DM_, DM_, QSCALE);
    k_gemmW<true, true, false><<<dim3(8, 32), 256, 0, stream>>>(x, Wk, bk, Kr, rtab, M_, DM_, DM_, 1.0f);
    k_gemmW<true, false, false><<<dim3(8, 32), 256, 0, stream>>>(x, Wv, bv, VpAO, rtab, M_, DM_, DM_, 1.0f);
  }
  k_vtrans<<<dim3(1024), 256, 0, stream>>>(VpAO, Vt);

  k_attn<<<dim3(1024), 256, 0, stream>>>(Qr, Kr, Vt, dist, tabb, VpAO);

  if (prep && xcast) {
    k_gemm2<false, true><<<dim3(8, 32), 256, 0, stream>>>(VpAO, Wto, bo, d_out, rtab, M_, DM_, DM_, 1.0f);
  } else {
    k_gemmW<false, false, true><<<dim3(8, 32), 256, 0, stream>>>(VpAO, Wo, bo, d_out, rtab, M_, DM_, DM_, 1.0f);
  }
}

// Round 12
// 245.178 us; speedup vs baseline: 1.6369x; 1.6369x over previous
//
#include <hip/hip_runtime.h>
#include <hip/hip_bf16.h>
#include <math.h>

#define B_   2
#define S_   2048
#define H_   16
#define DH_  64
#define DM_  1024
#define M_   (B_*S_)   // 4096
#define PV_  512
#define LOG2E 1.4426950408889634f

typedef __attribute__((ext_vector_type(8))) short bf16x8;
typedef __attribute__((ext_vector_type(4))) float f32x4;

__device__ __forceinline__ float b2f(unsigned short u) {
  union { unsigned int i; float f; } v; v.i = ((unsigned int)u) << 16; return v.f;
}
__device__ __forceinline__ unsigned short f2b(float f) {
  union { float f; unsigned int i; } v; v.f = f;
  return (unsigned short)((v.i + 0x7fffu + ((v.i >> 16) & 1u)) >> 16);  // RNE
}
__device__ __forceinline__ f32x4 mfma16(bf16x8 a, bf16x8 b, f32x4 c) {
  return __builtin_amdgcn_mfma_f32_16x16x32_bf16(a, b, c, 0, 0, 0);
}

// ---------------- RoPE sin/cos table: tab[s][i] = {sin, cos} (float2), i in [0,32)
__global__ void k_ropetab(float* tab) {
  int idx = blockIdx.x * 256 + threadIdx.x;       // s*32 + i
  if (idx >= S_ * 32) return;
  int s = idx >> 5, i = idx & 31;
  double inv = exp(-((double)(2 * i) / 64.0) * log(10000.0));
  double f = (double)s * inv;
  tab[idx * 2 + 0] = (float)sin(f);
  tab[idx * 2 + 1] = (float)cos(f);
}

// ---------------- one-time: x (f32) -> xb (bf16), 4096x1024 ---------------------
__global__ __launch_bounds__(256) void k_xcast(const float* __restrict__ x,
                                               unsigned short* __restrict__ xb) {
  int idx = blockIdx.x * 256 + threadIdx.x;       // chunks of 8
  const float4 f0 = *(const float4*)(x + (size_t)idx * 8);
  const float4 f1 = *(const float4*)(x + (size_t)idx * 8 + 4);
  union { uint4 u; unsigned short s[8]; } o;
  o.s[0] = f2b(f0.x); o.s[1] = f2b(f0.y); o.s[2] = f2b(f0.z); o.s[3] = f2b(f0.w);
  o.s[4] = f2b(f1.x); o.s[5] = f2b(f1.y); o.s[6] = f2b(f1.z); o.s[7] = f2b(f1.w);
  *(uint4*)(xb + (size_t)idx * 8) = o.u;
}

// ---------------- one-time: Wt[n][k] = bf16(W[k][n]), 1024x1024 ------------------
__global__ __launch_bounds__(256) void k_prepw(const float* __restrict__ W,
                                               unsigned short* __restrict__ Wt) {
  int r0 = blockIdx.y * 64, c0 = blockIdx.x * 64;  // r=k, c=n
  __shared__ unsigned short t[64][65];
  #pragma unroll
  for (int p = 0; p < 16; ++p) {
    int idx = p * 256 + threadIdx.x;
    int i = idx >> 6, j = idx & 63;
    t[i][j] = f2b(W[(size_t)(r0 + i) * DM_ + c0 + j]);
  }
  __syncthreads();
  #pragma unroll
  for (int p = 0; p < 16; ++p) {
    int idx = p * 256 + threadIdx.x;
    int i = idx >> 6, j = idx & 63;
    Wt[(size_t)(c0 + i) * DM_ + r0 + j] = t[j][i];
  }
}

// ---------------- GEMM (r9-verified): acc = A * W + bias -------------------------
// AF32: A f32 (else bf16). WB16: W pre-transposed bf16 [N][K] (else f32 [K][N]).
// OF32: write f32. ROPE: epilogue -> [b,h,s,d] bf16, scale folded.
template<bool AF32, bool ROPE, bool OF32, bool WB16>
__global__ __launch_bounds__(256) void k_gemmW(const void* __restrict__ Av,
                                               const void* __restrict__ Wv,
                                               const float* __restrict__ bias,
                                               void* __restrict__ Cv,
                                               const float* __restrict__ tab,
                                               int M, int N, int K, float scale) {
  __shared__ unsigned short Alds[128][40];
  __shared__ unsigned short Blds[128][40];
  int lane = threadIdx.x & 63, w = threadIdx.x >> 6;
  int wr = w >> 1, wc = w & 1;
  int l16 = lane & 15, lq = lane >> 4;
  int m0 = blockIdx.y * 128, n0 = blockIdx.x * 128;
  f32x4 acc[4][4];
  #pragma unroll
  for (int a = 0; a < 4; ++a)
    #pragma unroll
    for (int b = 0; b < 4; ++b) acc[a][b] = (f32x4){0.f, 0.f, 0.f, 0.f};

  for (int k0 = 0; k0 < K; k0 += 32) {
    __syncthreads();
    #pragma unroll
    for (int i = 0; i < 2; ++i) {
      int c = threadIdx.x + i * 256;
      int r = c >> 2, ch = (c & 3) * 8;
      size_t base = (size_t)(m0 + r) * K + k0 + ch;
      if (AF32) {
        const float* A = (const float*)Av;
        float4 f0 = *(const float4*)(A + base);
        float4 f1 = *(const float4*)(A + base + 4);
        unsigned short* dst = &Alds[r][ch];
        dst[0] = f2b(f0.x); dst[1] = f2b(f0.y); dst[2] = f2b(f0.z); dst[3] = f2b(f0.w);
        dst[4] = f2b(f1.x); dst[5] = f2b(f1.y); dst[6] = f2b(f1.z); dst[7] = f2b(f1.w);
      } else {
        *(uint4*)&Alds[r][ch] = *(const uint4*)((const unsigned short*)Av + base);
      }
    }
    if (WB16) {
      #pragma unroll
      for (int i = 0; i < 2; ++i) {
        int c = threadIdx.x + i * 256;
        int r = c >> 2, ch = (c & 3) * 8;
        *(uint4*)&Blds[r][ch] =
            *(const uint4*)((const unsigned short*)Wv + (size_t)(n0 + r) * K + k0 + ch);
      }
    } else {
      #pragma unroll
      for (int i = 0; i < 2; ++i) {
        int c = threadIdx.x + i * 256;
        int kk = c >> 4, n8 = (c & 15) * 8;
        size_t base = (size_t)(k0 + kk) * N + n0 + n8;
        const float* W = (const float*)Wv;
        float4 w0 = *(const float4*)(W + base);
        float4 w1 = *(const float4*)(W + base + 4);
        Blds[n8 + 0][kk] = f2b(w0.x); Blds[n8 + 1][kk] = f2b(w0.y);
        Blds[n8 + 2][kk] = f2b(w0.z); Blds[n8 + 3][kk] = f2b(w0.w);
        Blds[n8 + 4][kk] = f2b(w1.x); Blds[n8 + 5][kk] = f2b(w1.y);
        Blds[n8 + 6][kk] = f2b(w1.z); Blds[n8 + 7][kk] = f2b(w1.w);
      }
    }
    __syncthreads();
    bf16x8 af[4], bf_[4];
    #pragma unroll
    for (int mi = 0; mi < 4; ++mi) af[mi] = *(const bf16x8*)&Alds[wr * 64 + mi * 16 + l16][lq * 8];
    #pragma unroll
    for (int ni = 0; ni < 4; ++ni) bf_[ni] = *(const bf16x8*)&Blds[wc * 64 + ni * 16 + l16][lq * 8];
    #pragma unroll
    for (int mi = 0; mi < 4; ++mi)
      #pragma unroll
      for (int ni = 0; ni < 4; ++ni)
        acc[mi][ni] = mfma16(af[mi], bf_[ni], acc[mi][ni]);
  }
  // epilogue: C/D layout col=lane&15, row=(lane>>4)*4+j (m89)
  if (!ROPE) {
    #pragma unroll
    for (int ni = 0; ni < 4; ++ni) {
      int col = n0 + wc * 64 + ni * 16 + l16;
      float bv = bias[col];
      #pragma unroll
      for (int mi = 0; mi < 4; ++mi)
        #pragma unroll
        for (int j = 0; j < 4; ++j) {
          int row = m0 + wr * 64 + mi * 16 + lq * 4 + j;
          size_t idx = (size_t)row * N + col;
          float v = acc[mi][ni][j] + bv;
          if (OF32) ((float*)Cv)[idx] = v;
          else      ((unsigned short*)Cv)[idx] = f2b(v);
        }
    }
  } else {
    #pragma unroll
    for (int ni = 0; ni < 4; ++ni) {
      int col = n0 + wc * 64 + ni * 16 + l16;        // 0..1023 = h*64 + d
      int h = col >> 6, d = col & 63;
      float bv = bias[col];
      #pragma unroll
      for (int mi = 0; mi < 4; ++mi)
        #pragma unroll
        for (int j = 0; j < 4; ++j) {
          int row = m0 + wr * 64 + mi * 16 + lq * 4 + j;
          int s = row & (S_ - 1), b = row >> 11;
          float v = acc[mi][ni][j] + bv;
          float p = __shfl_xor(v, 1, 64);            // partner column value
          float2 sc = *(const float2*)(tab + ((size_t)s * 32 + (d >> 1)) * 2);
          float o = (d & 1) ? (v * sc.y + p * sc.x)
                            : (v * sc.y - p * sc.x);
          ((unsigned short*)Cv)[(((size_t)(b * H_ + h) * S_) + s) * DH_ + d] = f2b(o * scale);
        }
    }
  }
}

// ---------------- V: [b,s,h,d] -> Vt[b,h,d,s] (bf16 workspace) ------------------
__global__ __launch_bounds__(256) void k_vtrans(const unsigned short* __restrict__ Vp,
                                                unsigned short* __restrict__ Vt) {
  int bid = blockIdx.x;
  int st = bid & 31; int bh = bid >> 5; int h = bh & 15; int b = bh >> 4;
  int s0 = st * 64;
  __shared__ unsigned short t[64][72];
  #pragma unroll
  for (int i = 0; i < 2; ++i) {
    int c = threadIdx.x + i * 256;
    int r = c >> 3, ch = (c & 7) * 8;
    *(uint4*)&t[r][ch] = *(const uint4*)(Vp + (size_t)(b * S_ + s0 + r) * DM_ + h * DH_ + ch);
  }
  __syncthreads();
  #pragma unroll
  for (int i = 0; i < 2; ++i) {
    int c = threadIdx.x + i * 256;
    int dr = c >> 3, ch = (c & 7) * 8;
    union { uint4 u; unsigned short x[8]; } tb;
    #pragma unroll
    for (int e = 0; e < 8; ++e) tb.x[e] = t[ch + e][dr];
    *(uint4*)(Vt + ((size_t)bh * DH_ + dr) * S_ + s0 + ch) = tb.u;
  }
}

// ---------------- MFMA flash attention, 8-wave blocks, QBLK=128 -----------------
// block = (b, h, 128-row q tile); 8 waves, each owns 16 q rows.
// K/V staged once per kv-tile, shared by 8 waves (2x amortization vs r9).
__global__ __launch_bounds__(512) void k_attn(const unsigned short* __restrict__ Qr,
                                              const unsigned short* __restrict__ Kr,
                                              const unsigned short* __restrict__ Vt,
                                              const int* __restrict__ dist,
                                              const float* __restrict__ table,
                                              unsigned short* __restrict__ AO) {
  int bid = blockIdx.x;                            // (b*16+h)*16 + qt
  int qt = bid & 15; int bh = bid >> 4; int h = bh & 15; int b = bh >> 4;
  int lane = threadIdx.x & 63, w = threadIdx.x >> 6;   // w in [0,8)
  int l16 = lane & 15, lq = lane >> 4;
  int q0 = qt * 128;

  __shared__ unsigned short Klds[64][72];          // [key][d]
  __shared__ unsigned short Vlds[64][72];          // [d][key]
  __shared__ unsigned short Plds[8][16][72];       // per-wave P[qrow][key]
  __shared__ float tlds[PV_];                      // this head's bias column

  for (int i = threadIdx.x; i < PV_; i += 512) tlds[i] = table[i * H_ + h];

  const unsigned short* Qbase = Qr + ((size_t)bh * S_ + q0 + w * 16 + l16) * DH_;
  bf16x8 aq0 = *(const bf16x8*)(Qbase + lq * 8);
  bf16x8 aq1 = *(const bf16x8*)(Qbase + 32 + lq * 8);

  f32x4 oacc[4];
  float m_[4], l_[4];                              // per-lane partial l
  #pragma unroll
  for (int j = 0; j < 4; ++j) { m_[j] = -1e30f; l_[j] = 0.f; }
  #pragma unroll
  for (int td = 0; td < 4; ++td) oacc[td] = (f32x4){0.f, 0.f, 0.f, 0.f};

  const int* drow = dist + ((size_t)b * S_ + q0 + w * 16) * S_;
  const unsigned short* Ksrc0 = Kr + (size_t)bh * S_ * DH_;
  const unsigned short* Vsrc0 = Vt + (size_t)bh * DH_ * S_;

  int dc[4][4], dn[4][4];
  #pragma unroll
  for (int j = 0; j < 4; ++j) {
    const int* dr = drow + (size_t)(lq * 4 + j) * S_;
    #pragma unroll
    for (int t = 0; t < 4; ++t) dc[j][t] = dr[t * 16 + l16];
  }

  for (int kv = 0; kv < S_; kv += 64) {
    __syncthreads();                               // prev PV done before restage
    {
      const unsigned short* Ksrc = Ksrc0 + (size_t)kv * DH_;
      const unsigned short* Vsrc = Vsrc0 + kv;
      int c = threadIdx.x;                         // 512 threads = 512 chunks
      int r = c >> 3, ch = (c & 7) * 8;
      *(uint4*)&Klds[r][ch] = *(const uint4*)(Ksrc + (size_t)r * DH_ + ch);
      *(uint4*)&Vlds[r][ch] = *(const uint4*)(Vsrc + (size_t)r * S_ + ch);
    }
    {
      int kvn = (kv + 64 < S_) ? kv + 64 : 0;
      #pragma unroll
      for (int j = 0; j < 4; ++j) {
        const int* dr = drow + (size_t)(lq * 4 + j) * S_ + kvn;
        #pragma unroll
        for (int t = 0; t < 4; ++t) dn[j][t] = dr[t * 16 + l16];
      }
    }
    __syncthreads();

    f32x4 sc[4];
    #pragma unroll
    for (int t = 0; t < 4; ++t) {
      bf16x8 bk0 = *(const bf16x8*)&Klds[t * 16 + l16][lq * 8];
      bf16x8 bk1 = *(const bf16x8*)&Klds[t * 16 + l16][32 + lq * 8];
      f32x4 z = (f32x4){0.f, 0.f, 0.f, 0.f};
      z = mfma16(aq0, bk0, z);
      z = mfma16(aq1, bk1, z);
      sc[t] = z;
    }

    float rm[4];
    #pragma unroll
    for (int j = 0; j < 4; ++j) {
      float best = -1e30f;
      #pragma unroll
      for (int t = 0; t < 4; ++t) {
        int di = dc[j][t];
        float bv = (di >= 0) ? tlds[di < PV_ ? di : PV_ - 1] : 0.f;
        float s = sc[t][j] + bv;
        sc[t][j] = s;
        best = fmaxf(best, s);
      }
      rm[j] = best;
    }

    bool need = (rm[0] > m_[0] + 8.f) || (rm[1] > m_[1] + 8.f) ||
                (rm[2] > m_[2] + 8.f) || (rm[3] > m_[3] + 8.f);
    if (__any(need)) {
      #pragma unroll
      for (int off = 1; off < 16; off <<= 1) {
        #pragma unroll
        for (int j = 0; j < 4; ++j) rm[j] = fmaxf(rm[j], __shfl_xor(rm[j], off, 64));
      }
      #pragma unroll
      for (int j = 0; j < 4; ++j) {
        float mn = fmaxf(m_[j], rm[j]);
        float scl = exp2f((m_[j] - mn) * LOG2E);
        l_[j] *= scl;
        #pragma unroll
        for (int td = 0; td < 4; ++td) oacc[td][j] *= scl;
        m_[j] = mn;
      }
    }

    float p[4][4];
    #pragma unroll
    for (int j = 0; j < 4; ++j) {
      float su = 0.f;
      #pragma unroll
      for (int t = 0; t < 4; ++t) {
        float e = exp2f((sc[t][j] - m_[j]) * LOG2E);
        p[t][j] = e;
        su += e;
      }
      l_[j] += su;
    }

    #pragma unroll
    for (int j = 0; j < 4; ++j)
      #pragma unroll
      for (int t = 0; t < 4; ++t)
        Plds[w][lq * 4 + j][t * 16 + l16] = f2b(p[t][j]);

    bf16x8 pa0 = *(const bf16x8*)&Plds[w][l16][lq * 8];
    bf16x8 pa1 = *(const bf16x8*)&Plds[w][l16][32 + lq * 8];
    #pragma unroll
    for (int td = 0; td < 4; ++td) {
      bf16x8 v0 = *(const bf16x8*)&Vlds[td * 16 + l16][lq * 8];
      bf16x8 v1 = *(const bf16x8*)&Vlds[td * 16 + l16][32 + lq * 8];
      oacc[td] = mfma16(pa0, v0, oacc[td]);
      oacc[td] = mfma16(pa1, v1, oacc[td]);
    }

    #pragma unroll
    for (int j = 0; j < 4; ++j)
      #pragma unroll
      for (int t = 0; t < 4; ++t) dc[j][t] = dn[j][t];
  }

  #pragma unroll
  for (int off = 1; off < 16; off <<= 1) {
    #pragma unroll
    for (int j = 0; j < 4; ++j) l_[j] += __shfl_xor(l_[j], off, 64);
  }
  float inv[4];
  #pragma unroll
  for (int j = 0; j < 4; ++j) inv[j] = 1.f / l_[j];
  #pragma unroll
  for (int td = 0; td < 4; ++td) {
    #pragma unroll
    for (int j = 0; j < 4; ++j) {
      size_t row = (size_t)b * S_ + q0 + w * 16 + lq * 4 + j;
      AO[row * DM_ + h * DH_ + td * 16 + l16] = f2b(oacc[td][j] * inv[j]);
    }
  }
}

// --------------------------------------------------------------------------------
extern "C" void kernel_launch(void* const* d_in, const int* in_sizes, int n_in,
                              void* d_out, int out_size, void* d_ws, size_t ws_size,
                              hipStream_t stream) {
  const float* x    = (const float*)d_in[0];
  const int*   dist = (const int*)d_in[1];
  const float* Wq   = (const float*)d_in[2];
  const float* bq   = (const float*)d_in[3];
  const float* Wk   = (const float*)d_in[4];
  const float* bk   = (const float*)d_in[5];
  const float* Wv   = (const float*)d_in[6];
  const float* bv   = (const float*)d_in[7];
  const float* Wo   = (const float*)d_in[8];
  const float* bo   = (const float*)d_in[9];
  const float* tabb = (const float*)d_in[10];

  char* ws = (char*)d_ws;
  const size_t SZ_TAB = (size_t)S_ * 32 * 2 * 4;       // 512 KB
  const size_t SZ_T   = (size_t)M_ * DM_ * 2;          // 8 MB
  const size_t SZ_W   = (size_t)DM_ * DM_ * 2;         // 2 MB
  float* rtab = (float*)ws;
  size_t off = SZ_TAB;
  unsigned short* Qr   = (unsigned short*)(ws + off); off += SZ_T;
  unsigned short* Kr   = (unsigned short*)(ws + off); off += SZ_T;
  unsigned short* Vt   = (unsigned short*)(ws + off); off += SZ_T;
  unsigned short* VpAO = (unsigned short*)(ws + off); off += SZ_T;  // Vp, then AO
  unsigned short* Wtq  = (unsigned short*)(ws + off); off += SZ_W;
  unsigned short* Wtk  = (unsigned short*)(ws + off); off += SZ_W;
  unsigned short* Wtv  = (unsigned short*)(ws + off); off += SZ_W;
  unsigned short* Wto  = (unsigned short*)(ws + off); off += SZ_W;
  size_t off_prep = off;
  unsigned short* xb   = (unsigned short*)(ws + off); off += SZ_T;
  bool prep  = ws_size >= off_prep;                    // 40.5 MB: Wt path
  bool xcast = ws_size >= off;                         // 48.5 MB: + bf16 x

  const float QSCALE = 0.125f;                         // 1/sqrt(64)

  k_ropetab<<<dim3(256), dim3(256), 0, stream>>>(rtab);

  if (prep && xcast) {
    k_prepw<<<dim3(16, 16), 256, 0, stream>>>(Wq, Wtq);
    k_prepw<<<dim3(16, 16), 256, 0, stream>>>(Wk, Wtk);
    k_prepw<<<dim3(16, 16), 256, 0, stream>>>(Wv, Wtv);
    k_prepw<<<dim3(16, 16), 256, 0, stream>>>(Wo, Wto);
    k_xcast<<<dim3(M_ * DM_ / 8 / 256), 256, 0, stream>>>(x, xb);
    k_gemmW<false, true,  false, true><<<dim3(8, 32), 256, 0, stream>>>(xb, Wtq, bq, Qr, rtab, M_, DM_, DM_, QSCALE);
    k_gemmW<false, true,  false, true><<<dim3(8, 32), 256, 0, stream>>>(xb, Wtk, bk, Kr, rtab, M_, DM_, DM_, 1.0f);
    k_gemmW<false, false, false, true><<<dim3(8, 32), 256, 0, stream>>>(xb, Wtv, bv, VpAO, rtab, M_, DM_, DM_, 1.0f);
  } else {
    k_gemmW<true, true,  false, false><<<dim3(8, 32), 256, 0, stream>>>(x, Wq, bq, Qr, rtab, M_, DM_, DM_, QSCALE);
    k_gemmW<true, true,  false, false><<<dim3(8, 32), 256, 0, stream>>>(x, Wk, bk, Kr, rtab, M_, DM_, DM_, 1.0f);
    k_gemmW<true, false, false, false><<<dim3(8, 32), 256, 0, stream>>>(x, Wv, bv, VpAO, rtab, M_, DM_, DM_, 1.0f);
  }
  k_vtrans<<<dim3(1024), 256, 0, stream>>>(VpAO, Vt);

  // attention: 512 blocks x 512 threads (8 waves), QBLK=128
  k_attn<<<dim3(512), dim3(512), 0, stream>>>(Qr, Kr, Vt, dist, tabb, VpAO);

  if (prep && xcast) {
    k_gemmW<false, false, true, true><<<dim3(8, 32), 256, 0, stream>>>(VpAO, Wto, bo, d_out, rtab, M_, DM_, DM_, 1.0f);
  } else {
    k_gemmW<false, false, true, false><<<dim3(8, 32), 256, 0, stream>>>(VpAO, Wo, bo, d_out, rtab, M_, DM_, DM_, 1.0f);
  }
}

// Round 13
// 240.954 us; speedup vs baseline: 1.6656x; 1.0175x over previous
//
#include <hip/hip_runtime.h>
#include <hip/hip_bf16.h>
#include <math.h>

#define B_   2
#define S_   2048
#define H_   16
#define DH_  64
#define DM_  1024
#define M_   (B_*S_)   // 4096
#define PV_  512
#define LOG2E 1.4426950408889634f

typedef __attribute__((ext_vector_type(8))) short bf16x8;
typedef __attribute__((ext_vector_type(4))) float f32x4;

__device__ __forceinline__ float b2f(unsigned short u) {
  union { unsigned int i; float f; } v; v.i = ((unsigned int)u) << 16; return v.f;
}
__device__ __forceinline__ unsigned short f2b(float f) {
  union { float f; unsigned int i; } v; v.f = f;
  return (unsigned short)((v.i + 0x7fffu + ((v.i >> 16) & 1u)) >> 16);  // RNE
}
__device__ __forceinline__ f32x4 mfma16(bf16x8 a, bf16x8 b, f32x4 c) {
  return __builtin_amdgcn_mfma_f32_16x16x32_bf16(a, b, c, 0, 0, 0);
}
// packed f32x2 -> bf16x2 (RNE), one VALU op; lo = a, hi = b
__device__ __forceinline__ unsigned int cvtpk(float a, float b) {
  unsigned int r;
  asm("v_cvt_pk_bf16_f32 %0, %1, %2" : "=v"(r) : "v"(a), "v"(b));
  return r;
}

// ---------------- RoPE sin/cos table: tab[s][i] = {sin, cos} (float2), i in [0,32)
__global__ void k_ropetab(float* tab) {
  int idx = blockIdx.x * 256 + threadIdx.x;       // s*32 + i
  if (idx >= S_ * 32) return;
  int s = idx >> 5, i = idx & 31;
  double inv = exp(-((double)(2 * i) / 64.0) * log(10000.0));
  double f = (double)s * inv;
  tab[idx * 2 + 0] = (float)sin(f);
  tab[idx * 2 + 1] = (float)cos(f);
}

// ---------------- one-time: x (f32) -> xb (bf16), 4096x1024 ---------------------
__global__ __launch_bounds__(256) void k_xcast(const float* __restrict__ x,
                                               unsigned short* __restrict__ xb) {
  int idx = blockIdx.x * 256 + threadIdx.x;       // chunks of 8
  const float4 f0 = *(const float4*)(x + (size_t)idx * 8);
  const float4 f1 = *(const float4*)(x + (size_t)idx * 8 + 4);
  union { uint4 u; unsigned short s[8]; } o;
  o.s[0] = f2b(f0.x); o.s[1] = f2b(f0.y); o.s[2] = f2b(f0.z); o.s[3] = f2b(f0.w);
  o.s[4] = f2b(f1.x); o.s[5] = f2b(f1.y); o.s[6] = f2b(f1.z); o.s[7] = f2b(f1.w);
  *(uint4*)(xb + (size_t)idx * 8) = o.u;
}

// ---------------- one-time: Wt[n][k] = bf16(W[k][n]), 1024x1024 ------------------
__global__ __launch_bounds__(256) void k_prepw(const float* __restrict__ W,
                                               unsigned short* __restrict__ Wt) {
  int r0 = blockIdx.y * 64, c0 = blockIdx.x * 64;  // r=k, c=n
  __shared__ unsigned short t[64][65];
  #pragma unroll
  for (int p = 0; p < 16; ++p) {
    int idx = p * 256 + threadIdx.x;
    int i = idx >> 6, j = idx & 63;
    t[i][j] = f2b(W[(size_t)(r0 + i) * DM_ + c0 + j]);
  }
  __syncthreads();
  #pragma unroll
  for (int p = 0; p < 16; ++p) {
    int idx = p * 256 + threadIdx.x;
    int i = idx >> 6, j = idx & 63;
    Wt[(size_t)(c0 + i) * DM_ + r0 + j] = t[j][i];
  }
}

// ---------------- GEMM (r9-verified): acc = A * W + bias -------------------------
// AF32: A f32 (else bf16). WB16: W pre-transposed bf16 [N][K] (else f32 [K][N]).
// OF32: write f32. ROPE: epilogue -> [b,h,s,d] bf16, scale folded.
template<bool AF32, bool ROPE, bool OF32, bool WB16>
__global__ __launch_bounds__(256) void k_gemmW(const void* __restrict__ Av,
                                               const void* __restrict__ Wv,
                                               const float* __restrict__ bias,
                                               void* __restrict__ Cv,
                                               const float* __restrict__ tab,
                                               int M, int N, int K, float scale) {
  __shared__ unsigned short Alds[128][40];
  __shared__ unsigned short Blds[128][40];
  int lane = threadIdx.x & 63, w = threadIdx.x >> 6;
  int wr = w >> 1, wc = w & 1;
  int l16 = lane & 15, lq = lane >> 4;
  int m0 = blockIdx.y * 128, n0 = blockIdx.x * 128;
  f32x4 acc[4][4];
  #pragma unroll
  for (int a = 0; a < 4; ++a)
    #pragma unroll
    for (int b = 0; b < 4; ++b) acc[a][b] = (f32x4){0.f, 0.f, 0.f, 0.f};

  for (int k0 = 0; k0 < K; k0 += 32) {
    __syncthreads();
    #pragma unroll
    for (int i = 0; i < 2; ++i) {
      int c = threadIdx.x + i * 256;
      int r = c >> 2, ch = (c & 3) * 8;
      size_t base = (size_t)(m0 + r) * K + k0 + ch;
      if (AF32) {
        const float* A = (const float*)Av;
        float4 f0 = *(const float4*)(A + base);
        float4 f1 = *(const float4*)(A + base + 4);
        unsigned short* dst = &Alds[r][ch];
        dst[0] = f2b(f0.x); dst[1] = f2b(f0.y); dst[2] = f2b(f0.z); dst[3] = f2b(f0.w);
        dst[4] = f2b(f1.x); dst[5] = f2b(f1.y); dst[6] = f2b(f1.z); dst[7] = f2b(f1.w);
      } else {
        *(uint4*)&Alds[r][ch] = *(const uint4*)((const unsigned short*)Av + base);
      }
    }
    if (WB16) {
      #pragma unroll
      for (int i = 0; i < 2; ++i) {
        int c = threadIdx.x + i * 256;
        int r = c >> 2, ch = (c & 3) * 8;
        *(uint4*)&Blds[r][ch] =
            *(const uint4*)((const unsigned short*)Wv + (size_t)(n0 + r) * K + k0 + ch);
      }
    } else {
      #pragma unroll
      for (int i = 0; i < 2; ++i) {
        int c = threadIdx.x + i * 256;
        int kk = c >> 4, n8 = (c & 15) * 8;
        size_t base = (size_t)(k0 + kk) * N + n0 + n8;
        const float* W = (const float*)Wv;
        float4 w0 = *(const float4*)(W + base);
        float4 w1 = *(const float4*)(W + base + 4);
        Blds[n8 + 0][kk] = f2b(w0.x); Blds[n8 + 1][kk] = f2b(w0.y);
        Blds[n8 + 2][kk] = f2b(w0.z); Blds[n8 + 3][kk] = f2b(w0.w);
        Blds[n8 + 4][kk] = f2b(w1.x); Blds[n8 + 5][kk] = f2b(w1.y);
        Blds[n8 + 6][kk] = f2b(w1.z); Blds[n8 + 7][kk] = f2b(w1.w);
      }
    }
    __syncthreads();
    bf16x8 af[4], bf_[4];
    #pragma unroll
    for (int mi = 0; mi < 4; ++mi) af[mi] = *(const bf16x8*)&Alds[wr * 64 + mi * 16 + l16][lq * 8];
    #pragma unroll
    for (int ni = 0; ni < 4; ++ni) bf_[ni] = *(const bf16x8*)&Blds[wc * 64 + ni * 16 + l16][lq * 8];
    #pragma unroll
    for (int mi = 0; mi < 4; ++mi)
      #pragma unroll
      for (int ni = 0; ni < 4; ++ni)
        acc[mi][ni] = mfma16(af[mi], bf_[ni], acc[mi][ni]);
  }
  // epilogue: C/D layout col=lane&15, row=(lane>>4)*4+j (m89)
  if (!ROPE) {
    #pragma unroll
    for (int ni = 0; ni < 4; ++ni) {
      int col = n0 + wc * 64 + ni * 16 + l16;
      float bv = bias[col];
      #pragma unroll
      for (int mi = 0; mi < 4; ++mi)
        #pragma unroll
        for (int j = 0; j < 4; ++j) {
          int row = m0 + wr * 64 + mi * 16 + lq * 4 + j;
          size_t idx = (size_t)row * N + col;
          float v = acc[mi][ni][j] + bv;
          if (OF32) ((float*)Cv)[idx] = v;
          else      ((unsigned short*)Cv)[idx] = f2b(v);
        }
    }
  } else {
    #pragma unroll
    for (int ni = 0; ni < 4; ++ni) {
      int col = n0 + wc * 64 + ni * 16 + l16;        // 0..1023 = h*64 + d
      int h = col >> 6, d = col & 63;
      float bv = bias[col];
      #pragma unroll
      for (int mi = 0; mi < 4; ++mi)
        #pragma unroll
        for (int j = 0; j < 4; ++j) {
          int row = m0 + wr * 64 + mi * 16 + lq * 4 + j;
          int s = row & (S_ - 1), b = row >> 11;
          float v = acc[mi][ni][j] + bv;
          float p = __shfl_xor(v, 1, 64);            // partner column value
          float2 sc = *(const float2*)(tab + ((size_t)s * 32 + (d >> 1)) * 2);
          float o = (d & 1) ? (v * sc.y + p * sc.x)
                            : (v * sc.y - p * sc.x);
          ((unsigned short*)Cv)[(((size_t)(b * H_ + h) * S_) + s) * DH_ + d] = f2b(o * scale);
        }
    }
  }
}

// ---------------- V: [b,s,h,d] -> Vt[b,h,d,s] (bf16 workspace) ------------------
__global__ __launch_bounds__(256) void k_vtrans(const unsigned short* __restrict__ Vp,
                                                unsigned short* __restrict__ Vt) {
  int bid = blockIdx.x;
  int st = bid & 31; int bh = bid >> 5; int h = bh & 15; int b = bh >> 4;
  int s0 = st * 64;
  __shared__ unsigned short t[64][72];
  #pragma unroll
  for (int i = 0; i < 2; ++i) {
    int c = threadIdx.x + i * 256;
    int r = c >> 3, ch = (c & 7) * 8;
    *(uint4*)&t[r][ch] = *(const uint4*)(Vp + (size_t)(b * S_ + s0 + r) * DM_ + h * DH_ + ch);
  }
  __syncthreads();
  #pragma unroll
  for (int i = 0; i < 2; ++i) {
    int c = threadIdx.x + i * 256;
    int dr = c >> 3, ch = (c & 7) * 8;
    union { uint4 u; unsigned short x[8]; } tb;
    #pragma unroll
    for (int e = 0; e < 8; ++e) tb.x[e] = t[ch + e][dr];
    *(uint4*)(Vt + ((size_t)bh * DH_ + dr) * S_ + s0 + ch) = tb.u;
  }
}

// ---------------- MFMA flash attention, 8-wave QBLK=128, log2 domain ------------
// Qr pre-scaled by 0.125*LOG2E; tlds = bias*LOG2E; p = exp2(s - m).
// dist in [0,512) by construction -> direct gather, no guards.
__global__ __launch_bounds__(512) void k_attn(const unsigned short* __restrict__ Qr,
                                              const unsigned short* __restrict__ Kr,
                                              const unsigned short* __restrict__ Vt,
                                              const int* __restrict__ dist,
                                              const float* __restrict__ table,
                                              unsigned short* __restrict__ AO) {
  int bid = blockIdx.x;                            // (b*16+h)*16 + qt
  int qt = bid & 15; int bh = bid >> 4; int h = bh & 15; int b = bh >> 4;
  int lane = threadIdx.x & 63, w = threadIdx.x >> 6;   // w in [0,8)
  int l16 = lane & 15, lq = lane >> 4;
  int q0 = qt * 128;

  __shared__ unsigned short Klds[64][72];          // [key][d]
  __shared__ unsigned short Vlds[64][72];          // [d][key]
  __shared__ unsigned short Plds[8][16][72];       // per-wave P[qrow][key]
  __shared__ float tlds[PV_];                      // bias column * LOG2E

  for (int i = threadIdx.x; i < PV_; i += 512) tlds[i] = table[i * H_ + h] * LOG2E;

  const unsigned short* Qbase = Qr + ((size_t)bh * S_ + q0 + w * 16 + l16) * DH_;
  bf16x8 aq0 = *(const bf16x8*)(Qbase + lq * 8);
  bf16x8 aq1 = *(const bf16x8*)(Qbase + 32 + lq * 8);

  f32x4 oacc[4];
  float m_[4], l_[4];                              // per-lane partial l; m in log2 units
  #pragma unroll
  for (int j = 0; j < 4; ++j) { m_[j] = -1e30f; l_[j] = 0.f; }
  #pragma unroll
  for (int td = 0; td < 4; ++td) oacc[td] = (f32x4){0.f, 0.f, 0.f, 0.f};

  const int* drow = dist + ((size_t)b * S_ + q0 + w * 16) * S_;
  const unsigned short* Ksrc0 = Kr + (size_t)bh * S_ * DH_;
  const unsigned short* Vsrc0 = Vt + (size_t)bh * DH_ * S_;

  int dc[4][4], dn[4][4];
  #pragma unroll
  for (int j = 0; j < 4; ++j) {
    const int* dr = drow + (size_t)(lq * 4 + j) * S_;
    #pragma unroll
    for (int t = 0; t < 4; ++t) dc[j][t] = dr[t * 16 + l16];
  }

  for (int kv = 0; kv < S_; kv += 64) {
    __syncthreads();                               // prev PV done before restage
    {
      const unsigned short* Ksrc = Ksrc0 + (size_t)kv * DH_;
      const unsigned short* Vsrc = Vsrc0 + kv;
      int c = threadIdx.x;                         // 512 threads = 512 chunks
      int r = c >> 3, ch = (c & 7) * 8;
      *(uint4*)&Klds[r][ch] = *(const uint4*)(Ksrc + (size_t)r * DH_ + ch);
      *(uint4*)&Vlds[r][ch] = *(const uint4*)(Vsrc + (size_t)r * S_ + ch);
    }
    {
      int kvn = (kv + 64 < S_) ? kv + 64 : 0;
      #pragma unroll
      for (int j = 0; j < 4; ++j) {
        const int* dr = drow + (size_t)(lq * 4 + j) * S_ + kvn;
        #pragma unroll
        for (int t = 0; t < 4; ++t) dn[j][t] = dr[t * 16 + l16];
      }
    }
    __syncthreads();

    // S' = QK^T (log2 scale folded into Q)
    f32x4 sc[4];
    #pragma unroll
    for (int t = 0; t < 4; ++t) {
      bf16x8 bk0 = *(const bf16x8*)&Klds[t * 16 + l16][lq * 8];
      bf16x8 bk1 = *(const bf16x8*)&Klds[t * 16 + l16][32 + lq * 8];
      f32x4 z = (f32x4){0.f, 0.f, 0.f, 0.f};
      z = mfma16(aq0, bk0, z);
      z = mfma16(aq1, bk1, z);
      sc[t] = z;
    }

    // + bias (log2 domain, direct gather); per-lane row max
    float rm[4];
    #pragma unroll
    for (int j = 0; j < 4; ++j) {
      float best = -1e30f;
      #pragma unroll
      for (int t = 0; t < 4; ++t) {
        float s = sc[t][j] + tlds[dc[j][t]];
        sc[t][j] = s;
        best = fmaxf(best, s);
      }
      rm[j] = best;
    }

    // defer-max: rescale only if some lane's max grew past m + 8*LOG2E
    bool need = (rm[0] > m_[0] + 11.5416f) || (rm[1] > m_[1] + 11.5416f) ||
                (rm[2] > m_[2] + 11.5416f) || (rm[3] > m_[3] + 11.5416f);
    if (__any(need)) {
      #pragma unroll
      for (int off = 1; off < 16; off <<= 1) {
        #pragma unroll
        for (int j = 0; j < 4; ++j) rm[j] = fmaxf(rm[j], __shfl_xor(rm[j], off, 64));
      }
      #pragma unroll
      for (int j = 0; j < 4; ++j) {
        float mn = fmaxf(m_[j], rm[j]);
        float scl = exp2f(m_[j] - mn);
        l_[j] *= scl;
        #pragma unroll
        for (int td = 0; td < 4; ++td) oacc[td][j] *= scl;
        m_[j] = mn;
      }
    }

    // p = exp2(s' - m'); per-lane partial l
    float p[4][4];
    #pragma unroll
    for (int j = 0; j < 4; ++j) {
      float su = 0.f;
      #pragma unroll
      for (int t = 0; t < 4; ++t) {
        float e = exp2f(sc[t][j] - m_[j]);
        p[t][j] = e;
        su += e;
      }
      l_[j] += su;
    }

    // P -> per-wave LDS via packed cvt (same-wave RAW, no barrier)
    #pragma unroll
    for (int j = 0; j < 4; ++j) {
      unsigned int r01 = cvtpk(p[0][j], p[1][j]);
      unsigned int r23 = cvtpk(p[2][j], p[3][j]);
      Plds[w][lq * 4 + j][l16]      = (unsigned short)r01;
      Plds[w][lq * 4 + j][16 + l16] = (unsigned short)(r01 >> 16);
      Plds[w][lq * 4 + j][32 + l16] = (unsigned short)r23;
      Plds[w][lq * 4 + j][48 + l16] = (unsigned short)(r23 >> 16);
    }

    bf16x8 pa0 = *(const bf16x8*)&Plds[w][l16][lq * 8];
    bf16x8 pa1 = *(const bf16x8*)&Plds[w][l16][32 + lq * 8];
    #pragma unroll
    for (int td = 0; td < 4; ++td) {
      bf16x8 v0 = *(const bf16x8*)&Vlds[td * 16 + l16][lq * 8];
      bf16x8 v1 = *(const bf16x8*)&Vlds[td * 16 + l16][32 + lq * 8];
      oacc[td] = mfma16(pa0, v0, oacc[td]);
      oacc[td] = mfma16(pa1, v1, oacc[td]);
    }

    #pragma unroll
    for (int j = 0; j < 4; ++j)
      #pragma unroll
      for (int t = 0; t < 4; ++t) dc[j][t] = dn[j][t];
  }

  #pragma unroll
  for (int off = 1; off < 16; off <<= 1) {
    #pragma unroll
    for (int j = 0; j < 4; ++j) l_[j] += __shfl_xor(l_[j], off, 64);
  }
  float inv[4];
  #pragma unroll
  for (int j = 0; j < 4; ++j) inv[j] = 1.f / l_[j];
  #pragma unroll
  for (int td = 0; td < 4; ++td) {
    #pragma unroll
    for (int j = 0; j < 4; ++j) {
      size_t row = (size_t)b * S_ + q0 + w * 16 + lq * 4 + j;
      AO[row * DM_ + h * DH_ + td * 16 + l16] = f2b(oacc[td][j] * inv[j]);
    }
  }
}

// --------------------------------------------------------------------------------
extern "C" void kernel_launch(void* const* d_in, const int* in_sizes, int n_in,
                              void* d_out, int out_size, void* d_ws, size_t ws_size,
                              hipStream_t stream) {
  const float* x    = (const float*)d_in[0];
  const int*   dist = (const int*)d_in[1];
  const float* Wq   = (const float*)d_in[2];
  const float* bq   = (const float*)d_in[3];
  const float* Wk   = (const float*)d_in[4];
  const float* bk   = (const float*)d_in[5];
  const float* Wv   = (const float*)d_in[6];
  const float* bv   = (const float*)d_in[7];
  const float* Wo   = (const float*)d_in[8];
  const float* bo   = (const float*)d_in[9];
  const float* tabb = (const float*)d_in[10];

  char* ws = (char*)d_ws;
  const size_t SZ_TAB = (size_t)S_ * 32 * 2 * 4;       // 512 KB
  const size_t SZ_T   = (size_t)M_ * DM_ * 2;          // 8 MB
  const size_t SZ_W   = (size_t)DM_ * DM_ * 2;         // 2 MB
  float* rtab = (float*)ws;
  size_t off = SZ_TAB;
  unsigned short* Qr   = (unsigned short*)(ws + off); off += SZ_T;
  unsigned short* Kr   = (unsigned short*)(ws + off); off += SZ_T;
  unsigned short* Vt   = (unsigned short*)(ws + off); off += SZ_T;
  unsigned short* VpAO = (unsigned short*)(ws + off); off += SZ_T;  // Vp, then AO
  unsigned short* Wtq  = (unsigned short*)(ws + off); off += SZ_W;
  unsigned short* Wtk  = (unsigned short*)(ws + off); off += SZ_W;
  unsigned short* Wtv  = (unsigned short*)(ws + off); off += SZ_W;
  unsigned short* Wto  = (unsigned short*)(ws + off); off += SZ_W;
  size_t off_prep = off;
  unsigned short* xb   = (unsigned short*)(ws + off); off += SZ_T;
  bool prep  = ws_size >= off_prep;                    // 40.5 MB: Wt path
  bool xcast = ws_size >= off;                         // 48.5 MB: + bf16 x

  const float QSCALE = 0.125f * LOG2E;                 // 1/sqrt(64) * log2(e)

  k_ropetab<<<dim3(256), dim3(256), 0, stream>>>(rtab);

  if (prep && xcast) {
    k_prepw<<<dim3(16, 16), 256, 0, stream>>>(Wq, Wtq);
    k_prepw<<<dim3(16, 16), 256, 0, stream>>>(Wk, Wtk);
    k_prepw<<<dim3(16, 16), 256, 0, stream>>>(Wv, Wtv);
    k_prepw<<<dim3(16, 16), 256, 0, stream>>>(Wo, Wto);
    k_xcast<<<dim3(M_ * DM_ / 8 / 256), 256, 0, stream>>>(x, xb);
    k_gemmW<false, true,  false, true><<<dim3(8, 32), 256, 0, stream>>>(xb, Wtq, bq, Qr, rtab, M_, DM_, DM_, QSCALE);
    k_gemmW<false, true,  false, true><<<dim3(8, 32), 256, 0, stream>>>(xb, Wtk, bk, Kr, rtab, M_, DM_, DM_, 1.0f);
    k_gemmW<false, false, false, true><<<dim3(8, 32), 256, 0, stream>>>(xb, Wtv, bv, VpAO, rtab, M_, DM_, DM_, 1.0f);
  } else {
    k_gemmW<true, true,  false, false><<<dim3(8, 32), 256, 0, stream>>>(x, Wq, bq, Qr, rtab, M_, DM_, DM_, QSCALE);
    k_gemmW<true, true,  false, false><<<dim3(8, 32), 256, 0, stream>>>(x, Wk, bk, Kr, rtab, M_, DM_, DM_, 1.0f);
    k_gemmW<true, false, false, false><<<dim3(8, 32), 256, 0, stream>>>(x, Wv, bv, VpAO, rtab, M_, DM_, DM_, 1.0f);
  }
  k_vtrans<<<dim3(1024), 256, 0, stream>>>(VpAO, Vt);

  // attention: 512 blocks x 512 threads (8 waves), QBLK=128
  k_attn<<<dim3(512), dim3(512), 0, stream>>>(Qr, Kr, Vt, dist, tabb, VpAO);

  if (prep && xcast) {
    k_gemmW<false, false, true, true><<<dim3(8, 32), 256, 0, stream>>>(VpAO, Wto, bo, d_out, rtab, M_, DM_, DM_, 1.0f);
  } else {
    k_gemmW<false, false, true, false><<<dim3(8, 32), 256, 0, stream>>>(VpAO, Wo, bo, d_out, rtab, M_, DM_, DM_, 1.0f);
  }
}

// Round 14
// 219.702 us; speedup vs baseline: 1.8267x; 1.0967x over previous
//
#include <hip/hip_runtime.h>
#include <hip/hip_bf16.h>
#include <math.h>

#define B_   2
#define S_   2048
#define H_   16
#define DH_  64
#define DM_  1024
#define M_   (B_*S_)   // 4096
#define PV_  512
#define LOG2E 1.4426950408889634f

typedef __attribute__((ext_vector_type(8))) short bf16x8;
typedef __attribute__((ext_vector_type(4))) float f32x4;

__device__ __forceinline__ float b2f(unsigned short u) {
  union { unsigned int i; float f; } v; v.i = ((unsigned int)u) << 16; return v.f;
}
__device__ __forceinline__ unsigned short f2b(float f) {
  union { float f; unsigned int i; } v; v.f = f;
  return (unsigned short)((v.i + 0x7fffu + ((v.i >> 16) & 1u)) >> 16);  // RNE
}
__device__ __forceinline__ f32x4 mfma16(bf16x8 a, bf16x8 b, f32x4 c) {
  return __builtin_amdgcn_mfma_f32_16x16x32_bf16(a, b, c, 0, 0, 0);
}
// packed f32x2 -> bf16x2 (RNE), one VALU op; lo = a, hi = b
__device__ __forceinline__ unsigned int cvtpk(float a, float b) {
  unsigned int r;
  asm("v_cvt_pk_bf16_f32 %0, %1, %2" : "=v"(r) : "v"(a), "v"(b));
  return r;
}

// ---------------- fallback-only: RoPE table --------------------------------------
__global__ void k_ropetab(float* tab) {
  int idx = blockIdx.x * 256 + threadIdx.x;
  if (idx >= S_ * 32) return;
  int s = idx >> 5, i = idx & 31;
  double inv = exp(-((double)(2 * i) / 64.0) * log(10000.0));
  double f = (double)s * inv;
  tab[idx * 2 + 0] = (float)sin(f);
  tab[idx * 2 + 1] = (float)cos(f);
}

// ---------------- fused prep: ropetab + 4x W transpose->bf16 + xcast -------------
// blocks [0,256): ropetab; [256,1280): prepw (wid = (b-256)>>8); [1280,3328): xcast
__global__ __launch_bounds__(256) void k_prep(const float* __restrict__ x,
                                              const float* __restrict__ Wq,
                                              const float* __restrict__ Wk,
                                              const float* __restrict__ Wv,
                                              const float* __restrict__ Wo,
                                              float* __restrict__ tab,
                                              unsigned short* __restrict__ Wtall,
                                              unsigned short* __restrict__ xb) {
  __shared__ unsigned short t[64][65];
  int bid = blockIdx.x;
  if (bid < 256) {
    int idx = bid * 256 + threadIdx.x;             // < 65536 = S*32
    int s = idx >> 5, i = idx & 31;
    double inv = exp(-((double)(2 * i) / 64.0) * log(10000.0));
    double f = (double)s * inv;
    tab[idx * 2 + 0] = (float)sin(f);
    tab[idx * 2 + 1] = (float)cos(f);
  } else if (bid < 1280) {
    int tw = bid - 256;
    int wid = tw >> 8, sub = tw & 255;
    const float* W = (wid == 0) ? Wq : (wid == 1) ? Wk : (wid == 2) ? Wv : Wo;
    unsigned short* Wt = Wtall + (size_t)wid * DM_ * DM_;
    int r0 = (sub >> 4) * 64, c0 = (sub & 15) * 64;   // r=k, c=n
    #pragma unroll
    for (int p = 0; p < 16; ++p) {
      int idx = p * 256 + threadIdx.x;
      int i = idx >> 6, j = idx & 63;
      t[i][j] = f2b(W[(size_t)(r0 + i) * DM_ + c0 + j]);
    }
    __syncthreads();
    #pragma unroll
    for (int p = 0; p < 16; ++p) {
      int idx = p * 256 + threadIdx.x;
      int i = idx >> 6, j = idx & 63;
      Wt[(size_t)(c0 + i) * DM_ + r0 + j] = t[j][i];
    }
  } else {
    int idx = (bid - 1280) * 256 + threadIdx.x;    // chunks of 8, < 524288
    const float4 f0 = *(const float4*)(x + (size_t)idx * 8);
    const float4 f1 = *(const float4*)(x + (size_t)idx * 8 + 4);
    union { uint4 u; unsigned short s[8]; } o;
    o.s[0] = f2b(f0.x); o.s[1] = f2b(f0.y); o.s[2] = f2b(f0.z); o.s[3] = f2b(f0.w);
    o.s[4] = f2b(f1.x); o.s[5] = f2b(f1.y); o.s[6] = f2b(f1.z); o.s[7] = f2b(f1.w);
    *(uint4*)(xb + (size_t)idx * 8) = o.u;
  }
}

// ---------------- fused QKV GEMM: [4096x1024] x [1024x3072] + bias ---------------
// Wtall = bf16 [3072][1024] (pre-transposed, q|k|v). Epilogue by proj = n0>>10:
// proj 0 -> Qr (rope, qscale); 1 -> Kr (rope); 2 -> Vp (plain bf16).
__global__ __launch_bounds__(256) void k_gemmQKV(const unsigned short* __restrict__ A,
                                                 const unsigned short* __restrict__ Wtall,
                                                 const float* __restrict__ bq,
                                                 const float* __restrict__ bk,
                                                 const float* __restrict__ bv,
                                                 unsigned short* __restrict__ Qr,
                                                 unsigned short* __restrict__ Kr,
                                                 unsigned short* __restrict__ Vp,
                                                 const float* __restrict__ tab,
                                                 float qscale) {
  __shared__ unsigned short Alds[128][40];
  __shared__ unsigned short Blds[128][40];
  int lane = threadIdx.x & 63, w = threadIdx.x >> 6;
  int wr = w >> 1, wc = w & 1;
  int l16 = lane & 15, lq = lane >> 4;
  int m0 = blockIdx.y * 128, n0 = blockIdx.x * 128;
  f32x4 acc[4][4];
  #pragma unroll
  for (int a = 0; a < 4; ++a)
    #pragma unroll
    for (int b = 0; b < 4; ++b) acc[a][b] = (f32x4){0.f, 0.f, 0.f, 0.f};

  for (int k0 = 0; k0 < DM_; k0 += 32) {
    __syncthreads();
    #pragma unroll
    for (int i = 0; i < 2; ++i) {
      int c = threadIdx.x + i * 256;
      int r = c >> 2, ch = (c & 3) * 8;
      *(uint4*)&Alds[r][ch] = *(const uint4*)(A + (size_t)(m0 + r) * DM_ + k0 + ch);
      *(uint4*)&Blds[r][ch] = *(const uint4*)(Wtall + (size_t)(n0 + r) * DM_ + k0 + ch);
    }
    __syncthreads();
    bf16x8 af[4], bf_[4];
    #pragma unroll
    for (int mi = 0; mi < 4; ++mi) af[mi] = *(const bf16x8*)&Alds[wr * 64 + mi * 16 + l16][lq * 8];
    #pragma unroll
    for (int ni = 0; ni < 4; ++ni) bf_[ni] = *(const bf16x8*)&Blds[wc * 64 + ni * 16 + l16][lq * 8];
    #pragma unroll
    for (int mi = 0; mi < 4; ++mi)
      #pragma unroll
      for (int ni = 0; ni < 4; ++ni)
        acc[mi][ni] = mfma16(af[mi], bf_[ni], acc[mi][ni]);
  }

  // epilogue. proj uniform per block (128 cols within one 1024-col projection)
  int proj = n0 >> 10;
  const float* bs = (proj == 0) ? bq : (proj == 1) ? bk : bv;
  float scale = (proj == 0) ? qscale : 1.0f;
  unsigned short* R = (proj == 0) ? Qr : Kr;
  #pragma unroll
  for (int ni = 0; ni < 4; ++ni) {
    int col = n0 + wc * 64 + ni * 16 + l16;
    int c = col & 1023;
    float bvv = bs[c];
    if (proj < 2) {
      int h = c >> 6, d = c & 63;
      #pragma unroll
      for (int mi = 0; mi < 4; ++mi)
        #pragma unroll
        for (int j = 0; j < 4; ++j) {
          int row = m0 + wr * 64 + mi * 16 + lq * 4 + j;
          int s = row & (S_ - 1), b = row >> 11;
          float v = acc[mi][ni][j] + bvv;
          float p = __shfl_xor(v, 1, 64);            // partner column value
          float2 sc = *(const float2*)(tab + ((size_t)s * 32 + (d >> 1)) * 2);
          float o = (d & 1) ? (v * sc.y + p * sc.x)
                            : (v * sc.y - p * sc.x);
          R[(((size_t)(b * H_ + h) * S_) + s) * DH_ + d] = f2b(o * scale);
        }
    } else {
      #pragma unroll
      for (int mi = 0; mi < 4; ++mi)
        #pragma unroll
        for (int j = 0; j < 4; ++j) {
          int row = m0 + wr * 64 + mi * 16 + lq * 4 + j;
          Vp[(size_t)row * DM_ + c] = f2b(acc[mi][ni][j] + bvv);
        }
    }
  }
}

// ---------------- legacy GEMM (r9-verified; fallback + out-proj) ------------------
template<bool AF32, bool ROPE, bool OF32, bool WB16>
__global__ __launch_bounds__(256) void k_gemmW(const void* __restrict__ Av,
                                               const void* __restrict__ Wv,
                                               const float* __restrict__ bias,
                                               void* __restrict__ Cv,
                                               const float* __restrict__ tab,
                                               int M, int N, int K, float scale) {
  __shared__ unsigned short Alds[128][40];
  __shared__ unsigned short Blds[128][40];
  int lane = threadIdx.x & 63, w = threadIdx.x >> 6;
  int wr = w >> 1, wc = w & 1;
  int l16 = lane & 15, lq = lane >> 4;
  int m0 = blockIdx.y * 128, n0 = blockIdx.x * 128;
  f32x4 acc[4][4];
  #pragma unroll
  for (int a = 0; a < 4; ++a)
    #pragma unroll
    for (int b = 0; b < 4; ++b) acc[a][b] = (f32x4){0.f, 0.f, 0.f, 0.f};

  for (int k0 = 0; k0 < K; k0 += 32) {
    __syncthreads();
    #pragma unroll
    for (int i = 0; i < 2; ++i) {
      int c = threadIdx.x + i * 256;
      int r = c >> 2, ch = (c & 3) * 8;
      size_t base = (size_t)(m0 + r) * K + k0 + ch;
      if (AF32) {
        const float* A = (const float*)Av;
        float4 f0 = *(const float4*)(A + base);
        float4 f1 = *(const float4*)(A + base + 4);
        unsigned short* dst = &Alds[r][ch];
        dst[0] = f2b(f0.x); dst[1] = f2b(f0.y); dst[2] = f2b(f0.z); dst[3] = f2b(f0.w);
        dst[4] = f2b(f1.x); dst[5] = f2b(f1.y); dst[6] = f2b(f1.z); dst[7] = f2b(f1.w);
      } else {
        *(uint4*)&Alds[r][ch] = *(const uint4*)((const unsigned short*)Av + base);
      }
    }
    if (WB16) {
      #pragma unroll
      for (int i = 0; i < 2; ++i) {
        int c = threadIdx.x + i * 256;
        int r = c >> 2, ch = (c & 3) * 8;
        *(uint4*)&Blds[r][ch] =
            *(const uint4*)((const unsigned short*)Wv + (size_t)(n0 + r) * K + k0 + ch);
      }
    } else {
      #pragma unroll
      for (int i = 0; i < 2; ++i) {
        int c = threadIdx.x + i * 256;
        int kk = c >> 4, n8 = (c & 15) * 8;
        size_t base = (size_t)(k0 + kk) * N + n0 + n8;
        const float* W = (const float*)Wv;
        float4 w0 = *(const float4*)(W + base);
        float4 w1 = *(const float4*)(W + base + 4);
        Blds[n8 + 0][kk] = f2b(w0.x); Blds[n8 + 1][kk] = f2b(w0.y);
        Blds[n8 + 2][kk] = f2b(w0.z); Blds[n8 + 3][kk] = f2b(w0.w);
        Blds[n8 + 4][kk] = f2b(w1.x); Blds[n8 + 5][kk] = f2b(w1.y);
        Blds[n8 + 6][kk] = f2b(w1.z); Blds[n8 + 7][kk] = f2b(w1.w);
      }
    }
    __syncthreads();
    bf16x8 af[4], bf_[4];
    #pragma unroll
    for (int mi = 0; mi < 4; ++mi) af[mi] = *(const bf16x8*)&Alds[wr * 64 + mi * 16 + l16][lq * 8];
    #pragma unroll
    for (int ni = 0; ni < 4; ++ni) bf_[ni] = *(const bf16x8*)&Blds[wc * 64 + ni * 16 + l16][lq * 8];
    #pragma unroll
    for (int mi = 0; mi < 4; ++mi)
      #pragma unroll
      for (int ni = 0; ni < 4; ++ni)
        acc[mi][ni] = mfma16(af[mi], bf_[ni], acc[mi][ni]);
  }
  if (!ROPE) {
    #pragma unroll
    for (int ni = 0; ni < 4; ++ni) {
      int col = n0 + wc * 64 + ni * 16 + l16;
      float bv = bias[col];
      #pragma unroll
      for (int mi = 0; mi < 4; ++mi)
        #pragma unroll
        for (int j = 0; j < 4; ++j) {
          int row = m0 + wr * 64 + mi * 16 + lq * 4 + j;
          size_t idx = (size_t)row * N + col;
          float v = acc[mi][ni][j] + bv;
          if (OF32) ((float*)Cv)[idx] = v;
          else      ((unsigned short*)Cv)[idx] = f2b(v);
        }
    }
  } else {
    #pragma unroll
    for (int ni = 0; ni < 4; ++ni) {
      int col = n0 + wc * 64 + ni * 16 + l16;
      int h = col >> 6, d = col & 63;
      float bv = bias[col];
      #pragma unroll
      for (int mi = 0; mi < 4; ++mi)
        #pragma unroll
        for (int j = 0; j < 4; ++j) {
          int row = m0 + wr * 64 + mi * 16 + lq * 4 + j;
          int s = row & (S_ - 1), b = row >> 11;
          float v = acc[mi][ni][j] + bv;
          float p = __shfl_xor(v, 1, 64);
          float2 sc = *(const float2*)(tab + ((size_t)s * 32 + (d >> 1)) * 2);
          float o = (d & 1) ? (v * sc.y + p * sc.x)
                            : (v * sc.y - p * sc.x);
          ((unsigned short*)Cv)[(((size_t)(b * H_ + h) * S_) + s) * DH_ + d] = f2b(o * scale);
        }
    }
  }
}

// ---------------- V: [b,s,h,d] -> Vt[b,h,d,s] (bf16 workspace) ------------------
__global__ __launch_bounds__(256) void k_vtrans(const unsigned short* __restrict__ Vp,
                                                unsigned short* __restrict__ Vt) {
  int bid = blockIdx.x;
  int st = bid & 31; int bh = bid >> 5; int h = bh & 15; int b = bh >> 4;
  int s0 = st * 64;
  __shared__ unsigned short t[64][72];
  #pragma unroll
  for (int i = 0; i < 2; ++i) {
    int c = threadIdx.x + i * 256;
    int r = c >> 3, ch = (c & 7) * 8;
    *(uint4*)&t[r][ch] = *(const uint4*)(Vp + (size_t)(b * S_ + s0 + r) * DM_ + h * DH_ + ch);
  }
  __syncthreads();
  #pragma unroll
  for (int i = 0; i < 2; ++i) {
    int c = threadIdx.x + i * 256;
    int dr = c >> 3, ch = (c & 7) * 8;
    union { uint4 u; unsigned short x[8]; } tb;
    #pragma unroll
    for (int e = 0; e < 8; ++e) tb.x[e] = t[ch + e][dr];
    *(uint4*)(Vt + ((size_t)bh * DH_ + dr) * S_ + s0 + ch) = tb.u;
  }
}

// ---------------- MFMA flash attention, 8-wave QBLK=128, KVBLK=128, log2 --------
// Qr pre-scaled by 0.125*LOG2E; tlds = bias*LOG2E; p = exp2(s - m).
// dist in [0,512) by construction -> direct gather, no guards.
__global__ __launch_bounds__(512) void k_attn(const unsigned short* __restrict__ Qr,
                                              const unsigned short* __restrict__ Kr,
                                              const unsigned short* __restrict__ Vt,
                                              const int* __restrict__ dist,
                                              const float* __restrict__ table,
                                              unsigned short* __restrict__ AO) {
  int bid = blockIdx.x;                            // (b*16+h)*16 + qt
  int qt = bid & 15; int bh = bid >> 4; int h = bh & 15; int b = bh >> 4;
  int lane = threadIdx.x & 63, w = threadIdx.x >> 6;   // w in [0,8)
  int l16 = lane & 15, lq = lane >> 4;
  int q0 = qt * 128;

  __shared__ unsigned short Klds[128][72];         // [key][d]
  __shared__ unsigned short Vlds[64][136];         // [d][key] (128 keys + pad)
  __shared__ unsigned short Plds[8][16][72];       // per-wave P[qrow][key]
  __shared__ float tlds[PV_];                      // bias column * LOG2E

  for (int i = threadIdx.x; i < PV_; i += 512) tlds[i] = table[i * H_ + h] * LOG2E;

  const unsigned short* Qbase = Qr + ((size_t)bh * S_ + q0 + w * 16 + l16) * DH_;
  bf16x8 aq0 = *(const bf16x8*)(Qbase + lq * 8);
  bf16x8 aq1 = *(const bf16x8*)(Qbase + 32 + lq * 8);

  f32x4 oacc[4];
  float m_[4], l_[4];                              // per-lane partial l; m in log2 units
  #pragma unroll
  for (int j = 0; j < 4; ++j) { m_[j] = -1e30f; l_[j] = 0.f; }
  #pragma unroll
  for (int td = 0; td < 4; ++td) oacc[td] = (f32x4){0.f, 0.f, 0.f, 0.f};

  const int* drow = dist + ((size_t)b * S_ + q0 + w * 16) * S_;
  const unsigned short* Ksrc0 = Kr + (size_t)bh * S_ * DH_;
  const unsigned short* Vsrc0 = Vt + (size_t)bh * DH_ * S_;

  int dc[4][4], dn[4][4];
  #pragma unroll
  for (int j = 0; j < 4; ++j) {
    const int* dr = drow + (size_t)(lq * 4 + j) * S_;
    #pragma unroll
    for (int t = 0; t < 4; ++t) dc[j][t] = dr[t * 16 + l16];
  }

  for (int kv = 0; kv < S_; kv += 128) {
    __syncthreads();                               // prev PV done before restage
    {
      const unsigned short* Ksrc = Ksrc0 + (size_t)kv * DH_;
      const unsigned short* Vsrc = Vsrc0 + kv;
      #pragma unroll
      for (int i = 0; i < 2; ++i) {                // K: 128 rows x 8 chunks
        int c = threadIdx.x + i * 512;
        int r = c >> 3, ch = (c & 7) * 8;
        *(uint4*)&Klds[r][ch] = *(const uint4*)(Ksrc + (size_t)r * DH_ + ch);
      }
      #pragma unroll
      for (int i = 0; i < 2; ++i) {                // V: 64 d-rows x 16 chunks
        int c = threadIdx.x + i * 512;
        int r = c >> 4, ch = (c & 15) * 8;
        *(uint4*)&Vlds[r][ch] = *(const uint4*)(Vsrc + (size_t)r * S_ + ch);
      }
    }
    __syncthreads();

    #pragma unroll
    for (int sub = 0; sub < 2; ++sub) {
      int kb = sub * 64;
      // S' = QK^T (log2 scale folded into Q)
      f32x4 sc[4];
      __builtin_amdgcn_s_setprio(1);
      #pragma unroll
      for (int t = 0; t < 4; ++t) {
        bf16x8 bk0 = *(const bf16x8*)&Klds[kb + t * 16 + l16][lq * 8];
        bf16x8 bk1 = *(const bf16x8*)&Klds[kb + t * 16 + l16][32 + lq * 8];
        f32x4 z = (f32x4){0.f, 0.f, 0.f, 0.f};
        z = mfma16(aq0, bk0, z);
        z = mfma16(aq1, bk1, z);
        sc[t] = z;
      }
      __builtin_amdgcn_s_setprio(0);

      // prefetch next sub-tile's dist (sub1 for sub0; next kv's sub0 for sub1)
      {
        int kvn = (sub == 0) ? (kv + 64) : ((kv + 128 < S_) ? kv + 128 : 0);
        #pragma unroll
        for (int j = 0; j < 4; ++j) {
          const int* dr = drow + (size_t)(lq * 4 + j) * S_ + kvn;
          #pragma unroll
          for (int t = 0; t < 4; ++t) dn[j][t] = dr[t * 16 + l16];
        }
      }

      // + bias (log2 domain, direct gather); per-lane row max
      float rm[4];
      #pragma unroll
      for (int j = 0; j < 4; ++j) {
        float best = -1e30f;
        #pragma unroll
        for (int t = 0; t < 4; ++t) {
          float s = sc[t][j] + tlds[dc[j][t]];
          sc[t][j] = s;
          best = fmaxf(best, s);
        }
        rm[j] = best;
      }

      // defer-max: rescale only if some lane's max grew past m + 8*LOG2E
      bool need = (rm[0] > m_[0] + 11.5416f) || (rm[1] > m_[1] + 11.5416f) ||
                  (rm[2] > m_[2] + 11.5416f) || (rm[3] > m_[3] + 11.5416f);
      if (__any(need)) {
        #pragma unroll
        for (int off = 1; off < 16; off <<= 1) {
          #pragma unroll
          for (int j = 0; j < 4; ++j) rm[j] = fmaxf(rm[j], __shfl_xor(rm[j], off, 64));
        }
        #pragma unroll
        for (int j = 0; j < 4; ++j) {
          float mn = fmaxf(m_[j], rm[j]);
          float scl = exp2f(m_[j] - mn);
          l_[j] *= scl;
          #pragma unroll
          for (int td = 0; td < 4; ++td) oacc[td][j] *= scl;
          m_[j] = mn;
        }
      }

      // p = exp2(s' - m'); per-lane partial l
      float p[4][4];
      #pragma unroll
      for (int j = 0; j < 4; ++j) {
        float su = 0.f;
        #pragma unroll
        for (int t = 0; t < 4; ++t) {
          float e = exp2f(sc[t][j] - m_[j]);
          p[t][j] = e;
          su += e;
        }
        l_[j] += su;
      }

      // P -> per-wave LDS via packed cvt (same-wave RAW, no barrier)
      #pragma unroll
      for (int j = 0; j < 4; ++j) {
        unsigned int r01 = cvtpk(p[0][j], p[1][j]);
        unsigned int r23 = cvtpk(p[2][j], p[3][j]);
        Plds[w][lq * 4 + j][l16]      = (unsigned short)r01;
        Plds[w][lq * 4 + j][16 + l16] = (unsigned short)(r01 >> 16);
        Plds[w][lq * 4 + j][32 + l16] = (unsigned short)r23;
        Plds[w][lq * 4 + j][48 + l16] = (unsigned short)(r23 >> 16);
      }

      bf16x8 pa0 = *(const bf16x8*)&Plds[w][l16][lq * 8];
      bf16x8 pa1 = *(const bf16x8*)&Plds[w][l16][32 + lq * 8];
      __builtin_amdgcn_s_setprio(1);
      #pragma unroll
      for (int td = 0; td < 4; ++td) {
        bf16x8 v0 = *(const bf16x8*)&Vlds[td * 16 + l16][kb + lq * 8];
        bf16x8 v1 = *(const bf16x8*)&Vlds[td * 16 + l16][kb + 32 + lq * 8];
        oacc[td] = mfma16(pa0, v0, oacc[td]);
        oacc[td] = mfma16(pa1, v1, oacc[td]);
      }
      __builtin_amdgcn_s_setprio(0);

      #pragma unroll
      for (int j = 0; j < 4; ++j)
        #pragma unroll
        for (int t = 0; t < 4; ++t) dc[j][t] = dn[j][t];
    }
  }

  #pragma unroll
  for (int off = 1; off < 16; off <<= 1) {
    #pragma unroll
    for (int j = 0; j < 4; ++j) l_[j] += __shfl_xor(l_[j], off, 64);
  }
  float inv[4];
  #pragma unroll
  for (int j = 0; j < 4; ++j) inv[j] = 1.f / l_[j];
  #pragma unroll
  for (int td = 0; td < 4; ++td) {
    #pragma unroll
    for (int j = 0; j < 4; ++j) {
      size_t row = (size_t)b * S_ + q0 + w * 16 + lq * 4 + j;
      AO[row * DM_ + h * DH_ + td * 16 + l16] = f2b(oacc[td][j] * inv[j]);
    }
  }
}

// --------------------------------------------------------------------------------
extern "C" void kernel_launch(void* const* d_in, const int* in_sizes, int n_in,
                              void* d_out, int out_size, void* d_ws, size_t ws_size,
                              hipStream_t stream) {
  const float* x    = (const float*)d_in[0];
  const int*   dist = (const int*)d_in[1];
  const float* Wq   = (const float*)d_in[2];
  const float* bq   = (const float*)d_in[3];
  const float* Wk   = (const float*)d_in[4];
  const float* bk   = (const float*)d_in[5];
  const float* Wv   = (const float*)d_in[6];
  const float* bv   = (const float*)d_in[7];
  const float* Wo   = (const float*)d_in[8];
  const float* bo   = (const float*)d_in[9];
  const float* tabb = (const float*)d_in[10];

  char* ws = (char*)d_ws;
  const size_t SZ_TAB = (size_t)S_ * 32 * 2 * 4;       // 512 KB
  const size_t SZ_T   = (size_t)M_ * DM_ * 2;          // 8 MB
  const size_t SZ_W   = (size_t)DM_ * DM_ * 2;         // 2 MB
  float* rtab = (float*)ws;
  size_t off = SZ_TAB;
  unsigned short* Qr   = (unsigned short*)(ws + off); off += SZ_T;
  unsigned short* Kr   = (unsigned short*)(ws + off); off += SZ_T;
  unsigned short* Vt   = (unsigned short*)(ws + off); off += SZ_T;
  unsigned short* VpAO = (unsigned short*)(ws + off); off += SZ_T;  // Vp, then AO
  unsigned short* Wtall = (unsigned short*)(ws + off); off += 4 * SZ_W;  // q|k|v|o
  size_t off_prep = off;
  unsigned short* xb   = (unsigned short*)(ws + off); off += SZ_T;
  bool prep  = ws_size >= off_prep;                    // 40.5 MB: Wt path
  bool xcast = ws_size >= off;                         // 48.5 MB: + bf16 x

  const float QSCALE = 0.125f * LOG2E;                 // 1/sqrt(64) * log2(e)

  if (prep && xcast) {
    k_prep<<<dim3(3328), 256, 0, stream>>>(x, Wq, Wk, Wv, Wo, rtab, Wtall, xb);
    k_gemmQKV<<<dim3(24, 32), 256, 0, stream>>>(xb, Wtall, bq, bk, bv, Qr, Kr, VpAO, rtab, QSCALE);
  } else {
    k_ropetab<<<dim3(256), dim3(256), 0, stream>>>(rtab);
    k_gemmW<true, true,  false, false><<<dim3(8, 32), 256, 0, stream>>>(x, Wq, bq, Qr, rtab, M_, DM_, DM_, QSCALE);
    k_gemmW<true, true,  false, false><<<dim3(8, 32), 256, 0, stream>>>(x, Wk, bk, Kr, rtab, M_, DM_, DM_, 1.0f);
    k_gemmW<true, false, false, false><<<dim3(8, 32), 256, 0, stream>>>(x, Wv, bv, VpAO, rtab, M_, DM_, DM_, 1.0f);
  }
  k_vtrans<<<dim3(1024), 256, 0, stream>>>(VpAO, Vt);

  // attention: 512 blocks x 512 threads (8 waves), QBLK=128, KVBLK=128
  k_attn<<<dim3(512), dim3(512), 0, stream>>>(Qr, Kr, Vt, dist, tabb, VpAO);

  if (prep && xcast) {
    k_gemmW<false, false, true, true><<<dim3(8, 32), 256, 0, stream>>>(
        VpAO, Wtall + (size_t)3 * DM_ * DM_, bo, d_out, rtab, M_, DM_, DM_, 1.0f);
  } else {
    k_gemmW<false, false, true, false><<<dim3(8, 32), 256, 0, stream>>>(VpAO, Wo, bo, d_out, rtab, M_, DM_, DM_, 1.0f);
  }
}

// Round 15
// 203.944 us; speedup vs baseline: 1.9678x; 1.0773x over previous
//
#include <hip/hip_runtime.h>
#include <hip/hip_bf16.h>
#include <math.h>

#define B_   2
#define S_   2048
#define H_   16
#define DH_  64
#define DM_  1024
#define M_   (B_*S_)   // 4096
#define PV_  512
#define LOG2E 1.4426950408889634f

typedef __attribute__((ext_vector_type(8))) short bf16x8;
typedef __attribute__((ext_vector_type(4))) float f32x4;

__device__ __forceinline__ float b2f(unsigned short u) {
  union { unsigned int i; float f; } v; v.i = ((unsigned int)u) << 16; return v.f;
}
__device__ __forceinline__ unsigned short f2b(float f) {
  union { float f; unsigned int i; } v; v.f = f;
  return (unsigned short)((v.i + 0x7fffu + ((v.i >> 16) & 1u)) >> 16);  // RNE
}
__device__ __forceinline__ f32x4 mfma16(bf16x8 a, bf16x8 b, f32x4 c) {
  return __builtin_amdgcn_mfma_f32_16x16x32_bf16(a, b, c, 0, 0, 0);
}
// packed f32x2 -> bf16x2 (RNE), one VALU op; lo = a, hi = b
__device__ __forceinline__ unsigned int cvtpk(float a, float b) {
  unsigned int r;
  asm("v_cvt_pk_bf16_f32 %0, %1, %2" : "=v"(r) : "v"(a), "v"(b));
  return r;
}

// ---------------- fallback-only: RoPE table --------------------------------------
__global__ void k_ropetab(float* tab) {
  int idx = blockIdx.x * 256 + threadIdx.x;
  if (idx >= S_ * 32) return;
  int s = idx >> 5, i = idx & 31;
  double inv = exp(-((double)(2 * i) / 64.0) * log(10000.0));
  double f = (double)s * inv;
  tab[idx * 2 + 0] = (float)sin(f);
  tab[idx * 2 + 1] = (float)cos(f);
}

// ---------------- fused prep: ropetab + 4x W transpose->bf16 + xcast -------------
// blocks [0,256): ropetab; [256,1280): prepw (wid = (b-256)>>8); [1280,3328): xcast
__global__ __launch_bounds__(256) void k_prep(const float* __restrict__ x,
                                              const float* __restrict__ Wq,
                                              const float* __restrict__ Wk,
                                              const float* __restrict__ Wv,
                                              const float* __restrict__ Wo,
                                              float* __restrict__ tab,
                                              unsigned short* __restrict__ Wtall,
                                              unsigned short* __restrict__ xb) {
  __shared__ unsigned short t[64][65];
  int bid = blockIdx.x;
  if (bid < 256) {
    int idx = bid * 256 + threadIdx.x;             // < 65536 = S*32
    int s = idx >> 5, i = idx & 31;
    double inv = exp(-((double)(2 * i) / 64.0) * log(10000.0));
    double f = (double)s * inv;
    tab[idx * 2 + 0] = (float)sin(f);
    tab[idx * 2 + 1] = (float)cos(f);
  } else if (bid < 1280) {
    int tw = bid - 256;
    int wid = tw >> 8, sub = tw & 255;
    const float* W = (wid == 0) ? Wq : (wid == 1) ? Wk : (wid == 2) ? Wv : Wo;
    unsigned short* Wt = Wtall + (size_t)wid * DM_ * DM_;
    int r0 = (sub >> 4) * 64, c0 = (sub & 15) * 64;   // r=k, c=n
    #pragma unroll
    for (int p = 0; p < 16; ++p) {
      int idx = p * 256 + threadIdx.x;
      int i = idx >> 6, j = idx & 63;
      t[i][j] = f2b(W[(size_t)(r0 + i) * DM_ + c0 + j]);
    }
    __syncthreads();
    #pragma unroll
    for (int p = 0; p < 16; ++p) {
      int idx = p * 256 + threadIdx.x;
      int i = idx >> 6, j = idx & 63;
      Wt[(size_t)(c0 + i) * DM_ + r0 + j] = t[j][i];
    }
  } else {
    int idx = (bid - 1280) * 256 + threadIdx.x;    // chunks of 8, < 524288
    const float4 f0 = *(const float4*)(x + (size_t)idx * 8);
    const float4 f1 = *(const float4*)(x + (size_t)idx * 8 + 4);
    union { uint4 u; unsigned short s[8]; } o;
    o.s[0] = f2b(f0.x); o.s[1] = f2b(f0.y); o.s[2] = f2b(f0.z); o.s[3] = f2b(f0.w);
    o.s[4] = f2b(f1.x); o.s[5] = f2b(f1.y); o.s[6] = f2b(f1.z); o.s[7] = f2b(f1.w);
    *(uint4*)(xb + (size_t)idx * 8) = o.u;
  }
}

// ---------------- fused QKV GEMM: [4096x1024] x [1024x3072] + bias ---------------
// Wtall = bf16 [3072][1024] (pre-transposed, q|k|v). Epilogue by proj = n0>>10:
// proj 0 -> Qr (rope, qscale); 1 -> Kr (rope); 2 -> Vp (plain bf16).
__global__ __launch_bounds__(256) void k_gemmQKV(const unsigned short* __restrict__ A,
                                                 const unsigned short* __restrict__ Wtall,
                                                 const float* __restrict__ bq,
                                                 const float* __restrict__ bk,
                                                 const float* __restrict__ bv,
                                                 unsigned short* __restrict__ Qr,
                                                 unsigned short* __restrict__ Kr,
                                                 unsigned short* __restrict__ Vp,
                                                 const float* __restrict__ tab,
                                                 float qscale) {
  __shared__ unsigned short Alds[128][40];
  __shared__ unsigned short Blds[128][40];
  int lane = threadIdx.x & 63, w = threadIdx.x >> 6;
  int wr = w >> 1, wc = w & 1;
  int l16 = lane & 15, lq = lane >> 4;
  int m0 = blockIdx.y * 128, n0 = blockIdx.x * 128;
  f32x4 acc[4][4];
  #pragma unroll
  for (int a = 0; a < 4; ++a)
    #pragma unroll
    for (int b = 0; b < 4; ++b) acc[a][b] = (f32x4){0.f, 0.f, 0.f, 0.f};

  for (int k0 = 0; k0 < DM_; k0 += 32) {
    __syncthreads();
    #pragma unroll
    for (int i = 0; i < 2; ++i) {
      int c = threadIdx.x + i * 256;
      int r = c >> 2, ch = (c & 3) * 8;
      *(uint4*)&Alds[r][ch] = *(const uint4*)(A + (size_t)(m0 + r) * DM_ + k0 + ch);
      *(uint4*)&Blds[r][ch] = *(const uint4*)(Wtall + (size_t)(n0 + r) * DM_ + k0 + ch);
    }
    __syncthreads();
    bf16x8 af[4], bf_[4];
    #pragma unroll
    for (int mi = 0; mi < 4; ++mi) af[mi] = *(const bf16x8*)&Alds[wr * 64 + mi * 16 + l16][lq * 8];
    #pragma unroll
    for (int ni = 0; ni < 4; ++ni) bf_[ni] = *(const bf16x8*)&Blds[wc * 64 + ni * 16 + l16][lq * 8];
    #pragma unroll
    for (int mi = 0; mi < 4; ++mi)
      #pragma unroll
      for (int ni = 0; ni < 4; ++ni)
        acc[mi][ni] = mfma16(af[mi], bf_[ni], acc[mi][ni]);
  }

  // epilogue. proj uniform per block (128 cols within one 1024-col projection)
  int proj = n0 >> 10;
  const float* bs = (proj == 0) ? bq : (proj == 1) ? bk : bv;
  float scale = (proj == 0) ? qscale : 1.0f;
  unsigned short* R = (proj == 0) ? Qr : Kr;
  #pragma unroll
  for (int ni = 0; ni < 4; ++ni) {
    int col = n0 + wc * 64 + ni * 16 + l16;
    int c = col & 1023;
    float bvv = bs[c];
    if (proj < 2) {
      int h = c >> 6, d = c & 63;
      #pragma unroll
      for (int mi = 0; mi < 4; ++mi)
        #pragma unroll
        for (int j = 0; j < 4; ++j) {
          int row = m0 + wr * 64 + mi * 16 + lq * 4 + j;
          int s = row & (S_ - 1), b = row >> 11;
          float v = acc[mi][ni][j] + bvv;
          float p = __shfl_xor(v, 1, 64);            // partner column value
          float2 sc = *(const float2*)(tab + ((size_t)s * 32 + (d >> 1)) * 2);
          float o = (d & 1) ? (v * sc.y + p * sc.x)
                            : (v * sc.y - p * sc.x);
          R[(((size_t)(b * H_ + h) * S_) + s) * DH_ + d] = f2b(o * scale);
        }
    } else {
      #pragma unroll
      for (int mi = 0; mi < 4; ++mi)
        #pragma unroll
        for (int j = 0; j < 4; ++j) {
          int row = m0 + wr * 64 + mi * 16 + lq * 4 + j;
          Vp[(size_t)row * DM_ + c] = f2b(acc[mi][ni][j] + bvv);
        }
    }
  }
}

// ---------------- legacy GEMM (r9-verified; fallback + out-proj) ------------------
template<bool AF32, bool ROPE, bool OF32, bool WB16>
__global__ __launch_bounds__(256) void k_gemmW(const void* __restrict__ Av,
                                               const void* __restrict__ Wv,
                                               const float* __restrict__ bias,
                                               void* __restrict__ Cv,
                                               const float* __restrict__ tab,
                                               int M, int N, int K, float scale) {
  __shared__ unsigned short Alds[128][40];
  __shared__ unsigned short Blds[128][40];
  int lane = threadIdx.x & 63, w = threadIdx.x >> 6;
  int wr = w >> 1, wc = w & 1;
  int l16 = lane & 15, lq = lane >> 4;
  int m0 = blockIdx.y * 128, n0 = blockIdx.x * 128;
  f32x4 acc[4][4];
  #pragma unroll
  for (int a = 0; a < 4; ++a)
    #pragma unroll
    for (int b = 0; b < 4; ++b) acc[a][b] = (f32x4){0.f, 0.f, 0.f, 0.f};

  for (int k0 = 0; k0 < K; k0 += 32) {
    __syncthreads();
    #pragma unroll
    for (int i = 0; i < 2; ++i) {
      int c = threadIdx.x + i * 256;
      int r = c >> 2, ch = (c & 3) * 8;
      size_t base = (size_t)(m0 + r) * K + k0 + ch;
      if (AF32) {
        const float* A = (const float*)Av;
        float4 f0 = *(const float4*)(A + base);
        float4 f1 = *(const float4*)(A + base + 4);
        unsigned short* dst = &Alds[r][ch];
        dst[0] = f2b(f0.x); dst[1] = f2b(f0.y); dst[2] = f2b(f0.z); dst[3] = f2b(f0.w);
        dst[4] = f2b(f1.x); dst[5] = f2b(f1.y); dst[6] = f2b(f1.z); dst[7] = f2b(f1.w);
      } else {
        *(uint4*)&Alds[r][ch] = *(const uint4*)((const unsigned short*)Av + base);
      }
    }
    if (WB16) {
      #pragma unroll
      for (int i = 0; i < 2; ++i) {
        int c = threadIdx.x + i * 256;
        int r = c >> 2, ch = (c & 3) * 8;
        *(uint4*)&Blds[r][ch] =
            *(const uint4*)((const unsigned short*)Wv + (size_t)(n0 + r) * K + k0 + ch);
      }
    } else {
      #pragma unroll
      for (int i = 0; i < 2; ++i) {
        int c = threadIdx.x + i * 256;
        int kk = c >> 4, n8 = (c & 15) * 8;
        size_t base = (size_t)(k0 + kk) * N + n0 + n8;
        const float* W = (const float*)Wv;
        float4 w0 = *(const float4*)(W + base);
        float4 w1 = *(const float4*)(W + base + 4);
        Blds[n8 + 0][kk] = f2b(w0.x); Blds[n8 + 1][kk] = f2b(w0.y);
        Blds[n8 + 2][kk] = f2b(w0.z); Blds[n8 + 3][kk] = f2b(w0.w);
        Blds[n8 + 4][kk] = f2b(w1.x); Blds[n8 + 5][kk] = f2b(w1.y);
        Blds[n8 + 6][kk] = f2b(w1.z); Blds[n8 + 7][kk] = f2b(w1.w);
      }
    }
    __syncthreads();
    bf16x8 af[4], bf_[4];
    #pragma unroll
    for (int mi = 0; mi < 4; ++mi) af[mi] = *(const bf16x8*)&Alds[wr * 64 + mi * 16 + l16][lq * 8];
    #pragma unroll
    for (int ni = 0; ni < 4; ++ni) bf_[ni] = *(const bf16x8*)&Blds[wc * 64 + ni * 16 + l16][lq * 8];
    #pragma unroll
    for (int mi = 0; mi < 4; ++mi)
      #pragma unroll
      for (int ni = 0; ni < 4; ++ni)
        acc[mi][ni] = mfma16(af[mi], bf_[ni], acc[mi][ni]);
  }
  if (!ROPE) {
    #pragma unroll
    for (int ni = 0; ni < 4; ++ni) {
      int col = n0 + wc * 64 + ni * 16 + l16;
      float bv = bias[col];
      #pragma unroll
      for (int mi = 0; mi < 4; ++mi)
        #pragma unroll
        for (int j = 0; j < 4; ++j) {
          int row = m0 + wr * 64 + mi * 16 + lq * 4 + j;
          size_t idx = (size_t)row * N + col;
          float v = acc[mi][ni][j] + bv;
          if (OF32) ((float*)Cv)[idx] = v;
          else      ((unsigned short*)Cv)[idx] = f2b(v);
        }
    }
  } else {
    #pragma unroll
    for (int ni = 0; ni < 4; ++ni) {
      int col = n0 + wc * 64 + ni * 16 + l16;
      int h = col >> 6, d = col & 63;
      float bv = bias[col];
      #pragma unroll
      for (int mi = 0; mi < 4; ++mi)
        #pragma unroll
        for (int j = 0; j < 4; ++j) {
          int row = m0 + wr * 64 + mi * 16 + lq * 4 + j;
          int s = row & (S_ - 1), b = row >> 11;
          float v = acc[mi][ni][j] + bv;
          float p = __shfl_xor(v, 1, 64);
          float2 sc = *(const float2*)(tab + ((size_t)s * 32 + (d >> 1)) * 2);
          float o = (d & 1) ? (v * sc.y + p * sc.x)
                            : (v * sc.y - p * sc.x);
          ((unsigned short*)Cv)[(((size_t)(b * H_ + h) * S_) + s) * DH_ + d] = f2b(o * scale);
        }
    }
  }
}

// ---------------- V: [b,s,h,d] -> Vt[b,h,d,s] (bf16 workspace) ------------------
__global__ __launch_bounds__(256) void k_vtrans(const unsigned short* __restrict__ Vp,
                                                unsigned short* __restrict__ Vt) {
  int bid = blockIdx.x;
  int st = bid & 31; int bh = bid >> 5; int h = bh & 15; int b = bh >> 4;
  int s0 = st * 64;
  __shared__ unsigned short t[64][72];
  #pragma unroll
  for (int i = 0; i < 2; ++i) {
    int c = threadIdx.x + i * 256;
    int r = c >> 3, ch = (c & 7) * 8;
    *(uint4*)&t[r][ch] = *(const uint4*)(Vp + (size_t)(b * S_ + s0 + r) * DM_ + h * DH_ + ch);
  }
  __syncthreads();
  #pragma unroll
  for (int i = 0; i < 2; ++i) {
    int c = threadIdx.x + i * 256;
    int dr = c >> 3, ch = (c & 7) * 8;
    union { uint4 u; unsigned short x[8]; } tb;
    #pragma unroll
    for (int e = 0; e < 8; ++e) tb.x[e] = t[ch + e][dr];
    *(uint4*)(Vt + ((size_t)bh * DH_ + dr) * S_ + s0 + ch) = tb.u;
  }
}

// ---------------- MFMA flash attention (r13-verified, 115us) --------------------
// 8-wave QBLK=128, KVBLK=64, log2 domain. Qr pre-scaled by 0.125*LOG2E;
// tlds = bias*LOG2E; p = exp2(s - m). dist in [0,512) -> direct gather.
__global__ __launch_bounds__(512) void k_attn(const unsigned short* __restrict__ Qr,
                                              const unsigned short* __restrict__ Kr,
                                              const unsigned short* __restrict__ Vt,
                                              const int* __restrict__ dist,
                                              const float* __restrict__ table,
                                              unsigned short* __restrict__ AO) {
  int bid = blockIdx.x;                            // (b*16+h)*16 + qt
  int qt = bid & 15; int bh = bid >> 4; int h = bh & 15; int b = bh >> 4;
  int lane = threadIdx.x & 63, w = threadIdx.x >> 6;   // w in [0,8)
  int l16 = lane & 15, lq = lane >> 4;
  int q0 = qt * 128;

  __shared__ unsigned short Klds[64][72];          // [key][d]
  __shared__ unsigned short Vlds[64][72];          // [d][key]
  __shared__ unsigned short Plds[8][16][72];       // per-wave P[qrow][key]
  __shared__ float tlds[PV_];                      // bias column * LOG2E

  for (int i = threadIdx.x; i < PV_; i += 512) tlds[i] = table[i * H_ + h] * LOG2E;

  const unsigned short* Qbase = Qr + ((size_t)bh * S_ + q0 + w * 16 + l16) * DH_;
  bf16x8 aq0 = *(const bf16x8*)(Qbase + lq * 8);
  bf16x8 aq1 = *(const bf16x8*)(Qbase + 32 + lq * 8);

  f32x4 oacc[4];
  float m_[4], l_[4];                              // per-lane partial l; m in log2 units
  #pragma unroll
  for (int j = 0; j < 4; ++j) { m_[j] = -1e30f; l_[j] = 0.f; }
  #pragma unroll
  for (int td = 0; td < 4; ++td) oacc[td] = (f32x4){0.f, 0.f, 0.f, 0.f};

  const int* drow = dist + ((size_t)b * S_ + q0 + w * 16) * S_;
  const unsigned short* Ksrc0 = Kr + (size_t)bh * S_ * DH_;
  const unsigned short* Vsrc0 = Vt + (size_t)bh * DH_ * S_;

  int dc[4][4], dn[4][4];
  #pragma unroll
  for (int j = 0; j < 4; ++j) {
    const int* dr = drow + (size_t)(lq * 4 + j) * S_;
    #pragma unroll
    for (int t = 0; t < 4; ++t) dc[j][t] = dr[t * 16 + l16];
  }

  for (int kv = 0; kv < S_; kv += 64) {
    __syncthreads();                               // prev PV done before restage
    {
      const unsigned short* Ksrc = Ksrc0 + (size_t)kv * DH_;
      const unsigned short* Vsrc = Vsrc0 + kv;
      int c = threadIdx.x;                         // 512 threads = 512 chunks
      int r = c >> 3, ch = (c & 7) * 8;
      *(uint4*)&Klds[r][ch] = *(const uint4*)(Ksrc + (size_t)r * DH_ + ch);
      *(uint4*)&Vlds[r][ch] = *(const uint4*)(Vsrc + (size_t)r * S_ + ch);
    }
    {
      int kvn = (kv + 64 < S_) ? kv + 64 : 0;
      #pragma unroll
      for (int j = 0; j < 4; ++j) {
        const int* dr = drow + (size_t)(lq * 4 + j) * S_ + kvn;
        #pragma unroll
        for (int t = 0; t < 4; ++t) dn[j][t] = dr[t * 16 + l16];
      }
    }
    __syncthreads();

    // S' = QK^T (log2 scale folded into Q)
    f32x4 sc[4];
    #pragma unroll
    for (int t = 0; t < 4; ++t) {
      bf16x8 bk0 = *(const bf16x8*)&Klds[t * 16 + l16][lq * 8];
      bf16x8 bk1 = *(const bf16x8*)&Klds[t * 16 + l16][32 + lq * 8];
      f32x4 z = (f32x4){0.f, 0.f, 0.f, 0.f};
      z = mfma16(aq0, bk0, z);
      z = mfma16(aq1, bk1, z);
      sc[t] = z;
    }

    // + bias (log2 domain, direct gather); per-lane row max
    float rm[4];
    #pragma unroll
    for (int j = 0; j < 4; ++j) {
      float best = -1e30f;
      #pragma unroll
      for (int t = 0; t < 4; ++t) {
        float s = sc[t][j] + tlds[dc[j][t]];
        sc[t][j] = s;
        best = fmaxf(best, s);
      }
      rm[j] = best;
    }

    // defer-max: rescale only if some lane's max grew past m + 8*LOG2E
    bool need = (rm[0] > m_[0] + 11.5416f) || (rm[1] > m_[1] + 11.5416f) ||
                (rm[2] > m_[2] + 11.5416f) || (rm[3] > m_[3] + 11.5416f);
    if (__any(need)) {
      #pragma unroll
      for (int off = 1; off < 16; off <<= 1) {
        #pragma unroll
        for (int j = 0; j < 4; ++j) rm[j] = fmaxf(rm[j], __shfl_xor(rm[j], off, 64));
      }
      #pragma unroll
      for (int j = 0; j < 4; ++j) {
        float mn = fmaxf(m_[j], rm[j]);
        float scl = exp2f(m_[j] - mn);
        l_[j] *= scl;
        #pragma unroll
        for (int td = 0; td < 4; ++td) oacc[td][j] *= scl;
        m_[j] = mn;
      }
    }

    // p = exp2(s' - m'); per-lane partial l
    float p[4][4];
    #pragma unroll
    for (int j = 0; j < 4; ++j) {
      float su = 0.f;
      #pragma unroll
      for (int t = 0; t < 4; ++t) {
        float e = exp2f(sc[t][j] - m_[j]);
        p[t][j] = e;
        su += e;
      }
      l_[j] += su;
    }

    // P -> per-wave LDS via packed cvt (same-wave RAW, no barrier)
    #pragma unroll
    for (int j = 0; j < 4; ++j) {
      unsigned int r01 = cvtpk(p[0][j], p[1][j]);
      unsigned int r23 = cvtpk(p[2][j], p[3][j]);
      Plds[w][lq * 4 + j][l16]      = (unsigned short)r01;
      Plds[w][lq * 4 + j][16 + l16] = (unsigned short)(r01 >> 16);
      Plds[w][lq * 4 + j][32 + l16] = (unsigned short)r23;
      Plds[w][lq * 4 + j][48 + l16] = (unsigned short)(r23 >> 16);
    }

    bf16x8 pa0 = *(const bf16x8*)&Plds[w][l16][lq * 8];
    bf16x8 pa1 = *(const bf16x8*)&Plds[w][l16][32 + lq * 8];
    #pragma unroll
    for (int td = 0; td < 4; ++td) {
      bf16x8 v0 = *(const bf16x8*)&Vlds[td * 16 + l16][lq * 8];
      bf16x8 v1 = *(const bf16x8*)&Vlds[td * 16 + l16][32 + lq * 8];
      oacc[td] = mfma16(pa0, v0, oacc[td]);
      oacc[td] = mfma16(pa1, v1, oacc[td]);
    }

    #pragma unroll
    for (int j = 0; j < 4; ++j)
      #pragma unroll
      for (int t = 0; t < 4; ++t) dc[j][t] = dn[j][t];
  }

  #pragma unroll
  for (int off = 1; off < 16; off <<= 1) {
    #pragma unroll
    for (int j = 0; j < 4; ++j) l_[j] += __shfl_xor(l_[j], off, 64);
  }
  float inv[4];
  #pragma unroll
  for (int j = 0; j < 4; ++j) inv[j] = 1.f / l_[j];
  #pragma unroll
  for (int td = 0; td < 4; ++td) {
    #pragma unroll
    for (int j = 0; j < 4; ++j) {
      size_t row = (size_t)b * S_ + q0 + w * 16 + lq * 4 + j;
      AO[row * DM_ + h * DH_ + td * 16 + l16] = f2b(oacc[td][j] * inv[j]);
    }
  }
}

// --------------------------------------------------------------------------------
extern "C" void kernel_launch(void* const* d_in, const int* in_sizes, int n_in,
                              void* d_out, int out_size, void* d_ws, size_t ws_size,
                              hipStream_t stream) {
  const float* x    = (const float*)d_in[0];
  const int*   dist = (const int*)d_in[1];
  const float* Wq   = (const float*)d_in[2];
  const float* bq   = (const float*)d_in[3];
  const float* Wk   = (const float*)d_in[4];
  const float* bk   = (const float*)d_in[5];
  const float* Wv   = (const float*)d_in[6];
  const float* bv   = (const float*)d_in[7];
  const float* Wo   = (const float*)d_in[8];
  const float* bo   = (const float*)d_in[9];
  const float* tabb = (const float*)d_in[10];

  char* ws = (char*)d_ws;
  const size_t SZ_TAB = (size_t)S_ * 32 * 2 * 4;       // 512 KB
  const size_t SZ_T   = (size_t)M_ * DM_ * 2;          // 8 MB
  const size_t SZ_W   = (size_t)DM_ * DM_ * 2;         // 2 MB
  float* rtab = (float*)ws;
  size_t off = SZ_TAB;
  unsigned short* Qr   = (unsigned short*)(ws + off); off += SZ_T;
  unsigned short* Kr   = (unsigned short*)(ws + off); off += SZ_T;
  unsigned short* Vt   = (unsigned short*)(ws + off); off += SZ_T;
  unsigned short* VpAO = (unsigned short*)(ws + off); off += SZ_T;  // Vp, then AO
  unsigned short* Wtall = (unsigned short*)(ws + off); off += 4 * SZ_W;  // q|k|v|o
  size_t off_prep = off;
  unsigned short* xb   = (unsigned short*)(ws + off); off += SZ_T;
  bool prep  = ws_size >= off_prep;                    // 40.5 MB: Wt path
  bool xcast = ws_size >= off;                         // 48.5 MB: + bf16 x

  const float QSCALE = 0.125f * LOG2E;                 // 1/sqrt(64) * log2(e)

  if (prep && xcast) {
    k_prep<<<dim3(3328), 256, 0, stream>>>(x, Wq, Wk, Wv, Wo, rtab, Wtall, xb);
    k_gemmQKV<<<dim3(24, 32), 256, 0, stream>>>(xb, Wtall, bq, bk, bv, Qr, Kr, VpAO, rtab, QSCALE);
  } else {
    k_ropetab<<<dim3(256), dim3(256), 0, stream>>>(rtab);
    k_gemmW<true, true,  false, false><<<dim3(8, 32), 256, 0, stream>>>(x, Wq, bq, Qr, rtab, M_, DM_, DM_, QSCALE);
    k_gemmW<true, true,  false, false><<<dim3(8, 32), 256, 0, stream>>>(x, Wk, bk, Kr, rtab, M_, DM_, DM_, 1.0f);
    k_gemmW<true, false, false, false><<<dim3(8, 32), 256, 0, stream>>>(x, Wv, bv, VpAO, rtab, M_, DM_, DM_, 1.0f);
  }
  k_vtrans<<<dim3(1024), 256, 0, stream>>>(VpAO, Vt);

  // attention: 512 blocks x 512 threads (8 waves), QBLK=128, KVBLK=64 (r13)
  k_attn<<<dim3(512), dim3(512), 0, stream>>>(Qr, Kr, Vt, dist, tabb, VpAO);

  if (prep && xcast) {
    k_gemmW<false, false, true, true><<<dim3(8, 32), 256, 0, stream>>>(
        VpAO, Wtall + (size_t)3 * DM_ * DM_, bo, d_out, rtab, M_, DM_, DM_, 1.0f);
  } else {
    k_gemmW<false, false, true, false><<<dim3(8, 32), 256, 0, stream>>>(VpAO, Wo, bo, d_out, rtab, M_, DM_, DM_, 1.0f);
  }
}

// Round 16
// 191.160 us; speedup vs baseline: 2.0994x; 1.0669x over previous
//
#include <hip/hip_runtime.h>
#include <hip/hip_bf16.h>
#include <math.h>

#define B_   2
#define S_   2048
#define H_   16
#define DH_  64
#define DM_  1024
#define M_   (B_*S_)   // 4096
#define PV_  512
#define LOG2E 1.4426950408889634f

typedef __attribute__((ext_vector_type(8))) short bf16x8;
typedef __attribute__((ext_vector_type(4))) float f32x4;

__device__ __forceinline__ float b2f(unsigned short u) {
  union { unsigned int i; float f; } v; v.i = ((unsigned int)u) << 16; return v.f;
}
__device__ __forceinline__ unsigned short f2b(float f) {
  union { float f; unsigned int i; } v; v.f = f;
  return (unsigned short)((v.i + 0x7fffu + ((v.i >> 16) & 1u)) >> 16);  // RNE
}
__device__ __forceinline__ f32x4 mfma16(bf16x8 a, bf16x8 b, f32x4 c) {
  return __builtin_amdgcn_mfma_f32_16x16x32_bf16(a, b, c, 0, 0, 0);
}
// packed f32x2 -> bf16x2 (RNE), one VALU op; lo = a, hi = b
__device__ __forceinline__ unsigned int cvtpk(float a, float b) {
  unsigned int r;
  asm("v_cvt_pk_bf16_f32 %0, %1, %2" : "=v"(r) : "v"(a), "v"(b));
  return r;
}

// ---------------- fallback-only: RoPE table --------------------------------------
__global__ void k_ropetab(float* tab) {
  int idx = blockIdx.x * 256 + threadIdx.x;
  if (idx >= S_ * 32) return;
  int s = idx >> 5, i = idx & 31;
  double inv = exp(-((double)(2 * i) / 64.0) * log(10000.0));
  double f = (double)s * inv;
  tab[idx * 2 + 0] = (float)sin(f);
  tab[idx * 2 + 1] = (float)cos(f);
}

// ---------------- fused prep: ropetab + 4x W transpose->bf16 + xcast -------------
// blocks [0,256): ropetab; [256,1280): prepw (wid = (b-256)>>8); [1280,3328): xcast
__global__ __launch_bounds__(256) void k_prep(const float* __restrict__ x,
                                              const float* __restrict__ Wq,
                                              const float* __restrict__ Wk,
                                              const float* __restrict__ Wv,
                                              const float* __restrict__ Wo,
                                              float* __restrict__ tab,
                                              unsigned short* __restrict__ Wtall,
                                              unsigned short* __restrict__ xb) {
  __shared__ unsigned short t[64][65];
  int bid = blockIdx.x;
  if (bid < 256) {
    int idx = bid * 256 + threadIdx.x;             // < 65536 = S*32
    int s = idx >> 5, i = idx & 31;
    double inv = exp(-((double)(2 * i) / 64.0) * log(10000.0));
    double f = (double)s * inv;
    tab[idx * 2 + 0] = (float)sin(f);
    tab[idx * 2 + 1] = (float)cos(f);
  } else if (bid < 1280) {
    int tw = bid - 256;
    int wid = tw >> 8, sub = tw & 255;
    const float* W = (wid == 0) ? Wq : (wid == 1) ? Wk : (wid == 2) ? Wv : Wo;
    unsigned short* Wt = Wtall + (size_t)wid * DM_ * DM_;
    int r0 = (sub >> 4) * 64, c0 = (sub & 15) * 64;   // r=k, c=n
    #pragma unroll
    for (int p = 0; p < 16; ++p) {
      int idx = p * 256 + threadIdx.x;
      int i = idx >> 6, j = idx & 63;
      t[i][j] = f2b(W[(size_t)(r0 + i) * DM_ + c0 + j]);
    }
    __syncthreads();
    #pragma unroll
    for (int p = 0; p < 16; ++p) {
      int idx = p * 256 + threadIdx.x;
      int i = idx >> 6, j = idx & 63;
      Wt[(size_t)(c0 + i) * DM_ + r0 + j] = t[j][i];
    }
  } else {
    int idx = (bid - 1280) * 256 + threadIdx.x;    // chunks of 8, < 524288
    const float4 f0 = *(const float4*)(x + (size_t)idx * 8);
    const float4 f1 = *(const float4*)(x + (size_t)idx * 8 + 4);
    union { uint4 u; unsigned short s[8]; } o;
    o.s[0] = f2b(f0.x); o.s[1] = f2b(f0.y); o.s[2] = f2b(f0.z); o.s[3] = f2b(f0.w);
    o.s[4] = f2b(f1.x); o.s[5] = f2b(f1.y); o.s[6] = f2b(f1.z); o.s[7] = f2b(f1.w);
    *(uint4*)(xb + (size_t)idx * 8) = o.u;
  }
}

// ---------------- fused QKV GEMM: [4096x1024] x [1024x3072] + bias ---------------
// Wtall = bf16 [3072][1024] (pre-transposed, q|k|v). Epilogue by proj = n0>>10:
// proj 0 -> Qr (rope, qscale); 1 -> Kr (rope); 2 -> Vp (plain bf16).
__global__ __launch_bounds__(256) void k_gemmQKV(const unsigned short* __restrict__ A,
                                                 const unsigned short* __restrict__ Wtall,
                                                 const float* __restrict__ bq,
                                                 const float* __restrict__ bk,
                                                 const float* __restrict__ bv,
                                                 unsigned short* __restrict__ Qr,
                                                 unsigned short* __restrict__ Kr,
                                                 unsigned short* __restrict__ Vp,
                                                 const float* __restrict__ tab,
                                                 float qscale) {
  __shared__ unsigned short Alds[128][40];
  __shared__ unsigned short Blds[128][40];
  int lane = threadIdx.x & 63, w = threadIdx.x >> 6;
  int wr = w >> 1, wc = w & 1;
  int l16 = lane & 15, lq = lane >> 4;
  int m0 = blockIdx.y * 128, n0 = blockIdx.x * 128;
  f32x4 acc[4][4];
  #pragma unroll
  for (int a = 0; a < 4; ++a)
    #pragma unroll
    for (int b = 0; b < 4; ++b) acc[a][b] = (f32x4){0.f, 0.f, 0.f, 0.f};

  for (int k0 = 0; k0 < DM_; k0 += 32) {
    __syncthreads();
    #pragma unroll
    for (int i = 0; i < 2; ++i) {
      int c = threadIdx.x + i * 256;
      int r = c >> 2, ch = (c & 3) * 8;
      *(uint4*)&Alds[r][ch] = *(const uint4*)(A + (size_t)(m0 + r) * DM_ + k0 + ch);
      *(uint4*)&Blds[r][ch] = *(const uint4*)(Wtall + (size_t)(n0 + r) * DM_ + k0 + ch);
    }
    __syncthreads();
    bf16x8 af[4], bf_[4];
    #pragma unroll
    for (int mi = 0; mi < 4; ++mi) af[mi] = *(const bf16x8*)&Alds[wr * 64 + mi * 16 + l16][lq * 8];
    #pragma unroll
    for (int ni = 0; ni < 4; ++ni) bf_[ni] = *(const bf16x8*)&Blds[wc * 64 + ni * 16 + l16][lq * 8];
    #pragma unroll
    for (int mi = 0; mi < 4; ++mi)
      #pragma unroll
      for (int ni = 0; ni < 4; ++ni)
        acc[mi][ni] = mfma16(af[mi], bf_[ni], acc[mi][ni]);
  }

  // epilogue. proj uniform per block (128 cols within one 1024-col projection)
  int proj = n0 >> 10;
  const float* bs = (proj == 0) ? bq : (proj == 1) ? bk : bv;
  float scale = (proj == 0) ? qscale : 1.0f;
  unsigned short* R = (proj == 0) ? Qr : Kr;
  #pragma unroll
  for (int ni = 0; ni < 4; ++ni) {
    int col = n0 + wc * 64 + ni * 16 + l16;
    int c = col & 1023;
    float bvv = bs[c];
    if (proj < 2) {
      int h = c >> 6, d = c & 63;
      #pragma unroll
      for (int mi = 0; mi < 4; ++mi)
        #pragma unroll
        for (int j = 0; j < 4; ++j) {
          int row = m0 + wr * 64 + mi * 16 + lq * 4 + j;
          int s = row & (S_ - 1), b = row >> 11;
          float v = acc[mi][ni][j] + bvv;
          float p = __shfl_xor(v, 1, 64);            // partner column value
          float2 sc = *(const float2*)(tab + ((size_t)s * 32 + (d >> 1)) * 2);
          float o = (d & 1) ? (v * sc.y + p * sc.x)
                            : (v * sc.y - p * sc.x);
          R[(((size_t)(b * H_ + h) * S_) + s) * DH_ + d] = f2b(o * scale);
        }
    } else {
      #pragma unroll
      for (int mi = 0; mi < 4; ++mi)
        #pragma unroll
        for (int j = 0; j < 4; ++j) {
          int row = m0 + wr * 64 + mi * 16 + lq * 4 + j;
          Vp[(size_t)row * DM_ + c] = f2b(acc[mi][ni][j] + bvv);
        }
    }
  }
}

// ---------------- legacy GEMM (r9-verified; fallback + out-proj) ------------------
template<bool AF32, bool ROPE, bool OF32, bool WB16>
__global__ __launch_bounds__(256) void k_gemmW(const void* __restrict__ Av,
                                               const void* __restrict__ Wv,
                                               const float* __restrict__ bias,
                                               void* __restrict__ Cv,
                                               const float* __restrict__ tab,
                                               int M, int N, int K, float scale) {
  __shared__ unsigned short Alds[128][40];
  __shared__ unsigned short Blds[128][40];
  int lane = threadIdx.x & 63, w = threadIdx.x >> 6;
  int wr = w >> 1, wc = w & 1;
  int l16 = lane & 15, lq = lane >> 4;
  int m0 = blockIdx.y * 128, n0 = blockIdx.x * 128;
  f32x4 acc[4][4];
  #pragma unroll
  for (int a = 0; a < 4; ++a)
    #pragma unroll
    for (int b = 0; b < 4; ++b) acc[a][b] = (f32x4){0.f, 0.f, 0.f, 0.f};

  for (int k0 = 0; k0 < K; k0 += 32) {
    __syncthreads();
    #pragma unroll
    for (int i = 0; i < 2; ++i) {
      int c = threadIdx.x + i * 256;
      int r = c >> 2, ch = (c & 3) * 8;
      size_t base = (size_t)(m0 + r) * K + k0 + ch;
      if (AF32) {
        const float* A = (const float*)Av;
        float4 f0 = *(const float4*)(A + base);
        float4 f1 = *(const float4*)(A + base + 4);
        unsigned short* dst = &Alds[r][ch];
        dst[0] = f2b(f0.x); dst[1] = f2b(f0.y); dst[2] = f2b(f0.z); dst[3] = f2b(f0.w);
        dst[4] = f2b(f1.x); dst[5] = f2b(f1.y); dst[6] = f2b(f1.z); dst[7] = f2b(f1.w);
      } else {
        *(uint4*)&Alds[r][ch] = *(const uint4*)((const unsigned short*)Av + base);
      }
    }
    if (WB16) {
      #pragma unroll
      for (int i = 0; i < 2; ++i) {
        int c = threadIdx.x + i * 256;
        int r = c >> 2, ch = (c & 3) * 8;
        *(uint4*)&Blds[r][ch] =
            *(const uint4*)((const unsigned short*)Wv + (size_t)(n0 + r) * K + k0 + ch);
      }
    } else {
      #pragma unroll
      for (int i = 0; i < 2; ++i) {
        int c = threadIdx.x + i * 256;
        int kk = c >> 4, n8 = (c & 15) * 8;
        size_t base = (size_t)(k0 + kk) * N + n0 + n8;
        const float* W = (const float*)Wv;
        float4 w0 = *(const float4*)(W + base);
        float4 w1 = *(const float4*)(W + base + 4);
        Blds[n8 + 0][kk] = f2b(w0.x); Blds[n8 + 1][kk] = f2b(w0.y);
        Blds[n8 + 2][kk] = f2b(w0.z); Blds[n8 + 3][kk] = f2b(w0.w);
        Blds[n8 + 4][kk] = f2b(w1.x); Blds[n8 + 5][kk] = f2b(w1.y);
        Blds[n8 + 6][kk] = f2b(w1.z); Blds[n8 + 7][kk] = f2b(w1.w);
      }
    }
    __syncthreads();
    bf16x8 af[4], bf_[4];
    #pragma unroll
    for (int mi = 0; mi < 4; ++mi) af[mi] = *(const bf16x8*)&Alds[wr * 64 + mi * 16 + l16][lq * 8];
    #pragma unroll
    for (int ni = 0; ni < 4; ++ni) bf_[ni] = *(const bf16x8*)&Blds[wc * 64 + ni * 16 + l16][lq * 8];
    #pragma unroll
    for (int mi = 0; mi < 4; ++mi)
      #pragma unroll
      for (int ni = 0; ni < 4; ++ni)
        acc[mi][ni] = mfma16(af[mi], bf_[ni], acc[mi][ni]);
  }
  if (!ROPE) {
    #pragma unroll
    for (int ni = 0; ni < 4; ++ni) {
      int col = n0 + wc * 64 + ni * 16 + l16;
      float bv = bias[col];
      #pragma unroll
      for (int mi = 0; mi < 4; ++mi)
        #pragma unroll
        for (int j = 0; j < 4; ++j) {
          int row = m0 + wr * 64 + mi * 16 + lq * 4 + j;
          size_t idx = (size_t)row * N + col;
          float v = acc[mi][ni][j] + bv;
          if (OF32) ((float*)Cv)[idx] = v;
          else      ((unsigned short*)Cv)[idx] = f2b(v);
        }
    }
  } else {
    #pragma unroll
    for (int ni = 0; ni < 4; ++ni) {
      int col = n0 + wc * 64 + ni * 16 + l16;
      int h = col >> 6, d = col & 63;
      float bv = bias[col];
      #pragma unroll
      for (int mi = 0; mi < 4; ++mi)
        #pragma unroll
        for (int j = 0; j < 4; ++j) {
          int row = m0 + wr * 64 + mi * 16 + lq * 4 + j;
          int s = row & (S_ - 1), b = row >> 11;
          float v = acc[mi][ni][j] + bv;
          float p = __shfl_xor(v, 1, 64);
          float2 sc = *(const float2*)(tab + ((size_t)s * 32 + (d >> 1)) * 2);
          float o = (d & 1) ? (v * sc.y + p * sc.x)
                            : (v * sc.y - p * sc.x);
          ((unsigned short*)Cv)[(((size_t)(b * H_ + h) * S_) + s) * DH_ + d] = f2b(o * scale);
        }
    }
  }
}

// ---------------- V: [b,s,h,d] -> Vt[b,h,d,s] (bf16 workspace) ------------------
__global__ __launch_bounds__(256) void k_vtrans(const unsigned short* __restrict__ Vp,
                                                unsigned short* __restrict__ Vt) {
  int bid = blockIdx.x;
  int st = bid & 31; int bh = bid >> 5; int h = bh & 15; int b = bh >> 4;
  int s0 = st * 64;
  __shared__ unsigned short t[64][72];
  #pragma unroll
  for (int i = 0; i < 2; ++i) {
    int c = threadIdx.x + i * 256;
    int r = c >> 3, ch = (c & 7) * 8;
    *(uint4*)&t[r][ch] = *(const uint4*)(Vp + (size_t)(b * S_ + s0 + r) * DM_ + h * DH_ + ch);
  }
  __syncthreads();
  #pragma unroll
  for (int i = 0; i < 2; ++i) {
    int c = threadIdx.x + i * 256;
    int dr = c >> 3, ch = (c & 7) * 8;
    union { uint4 u; unsigned short x[8]; } tb;
    #pragma unroll
    for (int e = 0; e < 8; ++e) tb.x[e] = t[ch + e][dr];
    *(uint4*)(Vt + ((size_t)bh * DH_ + dr) * S_ + s0 + ch) = tb.u;
  }
}

// ---------------- MFMA flash attention, 8-wave QBLK=128, KVBLK=64, dbuf ----------
// 2-phase LDS double-buffer: ONE barrier/tile; next tile's loads issued before
// compute (latency hides under QK^T+softmax+PV), written after. Staging state =
// two named uint4 (no arrays -> no scratch). log2 domain as r13/r15.
__global__ __launch_bounds__(512) void k_attn(const unsigned short* __restrict__ Qr,
                                              const unsigned short* __restrict__ Kr,
                                              const unsigned short* __restrict__ Vt,
                                              const int* __restrict__ dist,
                                              const float* __restrict__ table,
                                              unsigned short* __restrict__ AO) {
  int bid = blockIdx.x;                            // (b*16+h)*16 + qt
  int qt = bid & 15; int bh = bid >> 4; int h = bh & 15; int b = bh >> 4;
  int lane = threadIdx.x & 63, w = threadIdx.x >> 6;   // w in [0,8)
  int l16 = lane & 15, lq = lane >> 4;
  int q0 = qt * 128;

  __shared__ unsigned short Klds[2][64][72];       // [buf][key][d]
  __shared__ unsigned short Vlds[2][64][72];       // [buf][d][key]
  __shared__ unsigned short Plds[8][16][72];       // per-wave P[qrow][key]
  __shared__ float tlds[PV_];                      // bias column * LOG2E

  for (int i = threadIdx.x; i < PV_; i += 512) tlds[i] = table[i * H_ + h] * LOG2E;

  const unsigned short* Qbase = Qr + ((size_t)bh * S_ + q0 + w * 16 + l16) * DH_;
  bf16x8 aq0 = *(const bf16x8*)(Qbase + lq * 8);
  bf16x8 aq1 = *(const bf16x8*)(Qbase + 32 + lq * 8);

  f32x4 oacc[4];
  float m_[4], l_[4];                              // per-lane partial l; m in log2 units
  #pragma unroll
  for (int j = 0; j < 4; ++j) { m_[j] = -1e30f; l_[j] = 0.f; }
  #pragma unroll
  for (int td = 0; td < 4; ++td) oacc[td] = (f32x4){0.f, 0.f, 0.f, 0.f};

  const int* drow = dist + ((size_t)b * S_ + q0 + w * 16) * S_;
  const unsigned short* Ksrc0 = Kr + (size_t)bh * S_ * DH_;
  const unsigned short* Vsrc0 = Vt + (size_t)bh * DH_ * S_;

  // staging decomposition: 512 threads stage 512 chunks (64 rows x 8 chunks)
  int sr = threadIdx.x >> 3, sch = (threadIdx.x & 7) * 8;

  int dc[4][4], dn[4][4];
  #pragma unroll
  for (int j = 0; j < 4; ++j) {
    const int* dr = drow + (size_t)(lq * 4 + j) * S_;
    #pragma unroll
    for (int t = 0; t < 4; ++t) dc[j][t] = dr[t * 16 + l16];
  }

  // prologue: tile 0 -> buf 0 (two named uint4, reused each iteration)
  uint4 krg = *(const uint4*)(Ksrc0 + (size_t)sr * DH_ + sch);
  uint4 vrg = *(const uint4*)(Vsrc0 + (size_t)sr * S_ + sch);
  *(uint4*)&Klds[0][sr][sch] = krg;
  *(uint4*)&Vlds[0][sr][sch] = vrg;

  int cur = 0;
  for (int kv = 0; kv < S_; kv += 64, cur ^= 1) {
    __syncthreads();                               // buf[cur] ready; buf[cur^1] free
    bool more = (kv + 64 < S_);
    if (more) {                                    // issue next tile's loads NOW
      krg = *(const uint4*)(Ksrc0 + (size_t)(kv + 64 + sr) * DH_ + sch);
      vrg = *(const uint4*)(Vsrc0 + (size_t)sr * S_ + kv + 64 + sch);
    }
    {
      int kvn = more ? kv + 64 : 0;
      #pragma unroll
      for (int j = 0; j < 4; ++j) {
        const int* dr = drow + (size_t)(lq * 4 + j) * S_ + kvn;
        #pragma unroll
        for (int t = 0; t < 4; ++t) dn[j][t] = dr[t * 16 + l16];
      }
    }

    // S' = QK^T (log2 scale folded into Q)
    f32x4 sc[4];
    #pragma unroll
    for (int t = 0; t < 4; ++t) {
      bf16x8 bk0 = *(const bf16x8*)&Klds[cur][t * 16 + l16][lq * 8];
      bf16x8 bk1 = *(const bf16x8*)&Klds[cur][t * 16 + l16][32 + lq * 8];
      f32x4 z = (f32x4){0.f, 0.f, 0.f, 0.f};
      z = mfma16(aq0, bk0, z);
      z = mfma16(aq1, bk1, z);
      sc[t] = z;
    }

    // + bias (log2 domain, direct gather); per-lane row max
    float rm[4];
    #pragma unroll
    for (int j = 0; j < 4; ++j) {
      float best = -1e30f;
      #pragma unroll
      for (int t = 0; t < 4; ++t) {
        float s = sc[t][j] + tlds[dc[j][t]];
        sc[t][j] = s;
        best = fmaxf(best, s);
      }
      rm[j] = best;
    }

    // defer-max: rescale only if some lane's max grew past m + 8*LOG2E
    bool need = (rm[0] > m_[0] + 11.5416f) || (rm[1] > m_[1] + 11.5416f) ||
                (rm[2] > m_[2] + 11.5416f) || (rm[3] > m_[3] + 11.5416f);
    if (__any(need)) {
      #pragma unroll
      for (int off = 1; off < 16; off <<= 1) {
        #pragma unroll
        for (int j = 0; j < 4; ++j) rm[j] = fmaxf(rm[j], __shfl_xor(rm[j], off, 64));
      }
      #pragma unroll
      for (int j = 0; j < 4; ++j) {
        float mn = fmaxf(m_[j], rm[j]);
        float scl = exp2f(m_[j] - mn);
        l_[j] *= scl;
        #pragma unroll
        for (int td = 0; td < 4; ++td) oacc[td][j] *= scl;
        m_[j] = mn;
      }
    }

    // p = exp2(s' - m'); per-lane partial l
    float p[4][4];
    #pragma unroll
    for (int j = 0; j < 4; ++j) {
      float su = 0.f;
      #pragma unroll
      for (int t = 0; t < 4; ++t) {
        float e = exp2f(sc[t][j] - m_[j]);
        p[t][j] = e;
        su += e;
      }
      l_[j] += su;
    }

    // P -> per-wave LDS via packed cvt (same-wave RAW, no barrier)
    #pragma unroll
    for (int j = 0; j < 4; ++j) {
      unsigned int r01 = cvtpk(p[0][j], p[1][j]);
      unsigned int r23 = cvtpk(p[2][j], p[3][j]);
      Plds[w][lq * 4 + j][l16]      = (unsigned short)r01;
      Plds[w][lq * 4 + j][16 + l16] = (unsigned short)(r01 >> 16);
      Plds[w][lq * 4 + j][32 + l16] = (unsigned short)r23;
      Plds[w][lq * 4 + j][48 + l16] = (unsigned short)(r23 >> 16);
    }

    bf16x8 pa0 = *(const bf16x8*)&Plds[w][l16][lq * 8];
    bf16x8 pa1 = *(const bf16x8*)&Plds[w][l16][32 + lq * 8];
    #pragma unroll
    for (int td = 0; td < 4; ++td) {
      bf16x8 v0 = *(const bf16x8*)&Vlds[cur][td * 16 + l16][lq * 8];
      bf16x8 v1 = *(const bf16x8*)&Vlds[cur][td * 16 + l16][32 + lq * 8];
      oacc[td] = mfma16(pa0, v0, oacc[td]);
      oacc[td] = mfma16(pa1, v1, oacc[td]);
    }

    // write next tile into the idle buffer; rotate dist regs
    if (more) {
      *(uint4*)&Klds[cur ^ 1][sr][sch] = krg;
      *(uint4*)&Vlds[cur ^ 1][sr][sch] = vrg;
      #pragma unroll
      for (int j = 0; j < 4; ++j)
        #pragma unroll
        for (int t = 0; t < 4; ++t) dc[j][t] = dn[j][t];
    }
  }

  #pragma unroll
  for (int off = 1; off < 16; off <<= 1) {
    #pragma unroll
    for (int j = 0; j < 4; ++j) l_[j] += __shfl_xor(l_[j], off, 64);
  }
  float inv[4];
  #pragma unroll
  for (int j = 0; j < 4; ++j) inv[j] = 1.f / l_[j];
  #pragma unroll
  for (int td = 0; td < 4; ++td) {
    #pragma unroll
    for (int j = 0; j < 4; ++j) {
      size_t row = (size_t)b * S_ + q0 + w * 16 + lq * 4 + j;
      AO[row * DM_ + h * DH_ + td * 16 + l16] = f2b(oacc[td][j] * inv[j]);
    }
  }
}

// --------------------------------------------------------------------------------
extern "C" void kernel_launch(void* const* d_in, const int* in_sizes, int n_in,
                              void* d_out, int out_size, void* d_ws, size_t ws_size,
                              hipStream_t stream) {
  const float* x    = (const float*)d_in[0];
  const int*   dist = (const int*)d_in[1];
  const float* Wq   = (const float*)d_in[2];
  const float* bq   = (const float*)d_in[3];
  const float* Wk   = (const float*)d_in[4];
  const float* bk   = (const float*)d_in[5];
  const float* Wv   = (const float*)d_in[6];
  const float* bv   = (const float*)d_in[7];
  const float* Wo   = (const float*)d_in[8];
  const float* bo   = (const float*)d_in[9];
  const float* tabb = (const float*)d_in[10];

  char* ws = (char*)d_ws;
  const size_t SZ_TAB = (size_t)S_ * 32 * 2 * 4;       // 512 KB
  const size_t SZ_T   = (size_t)M_ * DM_ * 2;          // 8 MB
  const size_t SZ_W   = (size_t)DM_ * DM_ * 2;         // 2 MB
  float* rtab = (float*)ws;
  size_t off = SZ_TAB;
  unsigned short* Qr   = (unsigned short*)(ws + off); off += SZ_T;
  unsigned short* Kr   = (unsigned short*)(ws + off); off += SZ_T;
  unsigned short* Vt   = (unsigned short*)(ws + off); off += SZ_T;
  unsigned short* VpAO = (unsigned short*)(ws + off); off += SZ_T;  // Vp, then AO
  unsigned short* Wtall = (unsigned short*)(ws + off); off += 4 * SZ_W;  // q|k|v|o
  size_t off_prep = off;
  unsigned short* xb   = (unsigned short*)(ws + off); off += SZ_T;
  bool prep  = ws_size >= off_prep;                    // 40.5 MB: Wt path
  bool xcast = ws_size >= off;                         // 48.5 MB: + bf16 x

  const float QSCALE = 0.125f * LOG2E;                 // 1/sqrt(64) * log2(e)

  if (prep && xcast) {
    k_prep<<<dim3(3328), 256, 0, stream>>>(x, Wq, Wk, Wv, Wo, rtab, Wtall, xb);
    k_gemmQKV<<<dim3(24, 32), 256, 0, stream>>>(xb, Wtall, bq, bk, bv, Qr, Kr, VpAO, rtab, QSCALE);
  } else {
    k_ropetab<<<dim3(256), dim3(256), 0, stream>>>(rtab);
    k_gemmW<true, true,  false, false><<<dim3(8, 32), 256, 0, stream>>>(x, Wq, bq, Qr, rtab, M_, DM_, DM_, QSCALE);
    k_gemmW<true, true,  false, false><<<dim3(8, 32), 256, 0, stream>>>(x, Wk, bk, Kr, rtab, M_, DM_, DM_, 1.0f);
    k_gemmW<true, false, false, false><<<dim3(8, 32), 256, 0, stream>>>(x, Wv, bv, VpAO, rtab, M_, DM_, DM_, 1.0f);
  }
  k_vtrans<<<dim3(1024), 256, 0, stream>>>(VpAO, Vt);

  // attention: 512 blocks x 512 threads (8 waves), QBLK=128, KVBLK=64, dbuf
  k_attn<<<dim3(512), dim3(512), 0, stream>>>(Qr, Kr, Vt, dist, tabb, VpAO);

  if (prep && xcast) {
    k_gemmW<false, false, true, true><<<dim3(8, 32), 256, 0, stream>>>(
        VpAO, Wtall + (size_t)3 * DM_ * DM_, bo, d_out, rtab, M_, DM_, DM_, 1.0f);
  } else {
    k_gemmW<false, false, true, false><<<dim3(8, 32), 256, 0, stream>>>(VpAO, Wo, bo, d_out, rtab, M_, DM_, DM_, 1.0f);
  }
}